// Round 12
// baseline (426.838 us; speedup 1.0000x reference)
//
#include <hip/hip_runtime.h>

#define N_NODES 50000
#define N_EDGES 800000
#define E_TOT (N_EDGES + N_NODES)
#define D 128
#define N_GRAPHS 64
#define NEG_SLOPE 0.2f
#define MAXDEG 256
#define SCAN_BLK 1024
#define SCAN_GRID ((N_NODES + SCAN_BLK - 1) / SCAN_BLK)   // 49

typedef _Float16 f16x8 __attribute__((ext_vector_type(8)));
typedef float f32x4 __attribute__((ext_vector_type(4)));

__device__ __forceinline__ float wave_max(float v) {
  #pragma unroll
  for (int off = 32; off > 0; off >>= 1) v = fmaxf(v, __shfl_xor(v, off));
  return v;
}
__device__ __forceinline__ float wave_sum(float v) {
  #pragma unroll
  for (int off = 32; off > 0; off >>= 1) v += __shfl_xor(v, off);
  return v;
}

// ---------------- CSR build ----------------
__global__ void k_count(const int* __restrict__ ei, int* __restrict__ cnt) {
  int e = blockIdx.x * blockDim.x + threadIdx.x;
  if (e >= E_TOT) return;
  int dst = (e < N_EDGES) ? ei[N_EDGES + e] : (e - N_EDGES);
  atomicAdd(&cnt[dst], 1);
}

__global__ __launch_bounds__(SCAN_BLK) void k_scan1(const int* __restrict__ cnt,
                                                    int* __restrict__ rowptr,
                                                    int* __restrict__ partial) {
  __shared__ int sm[SCAN_BLK];
  int i = blockIdx.x * SCAN_BLK + threadIdx.x;
  int v = (i < N_NODES) ? cnt[i] : 0;
  sm[threadIdx.x] = v;
  __syncthreads();
  #pragma unroll
  for (int off = 1; off < SCAN_BLK; off <<= 1) {
    int t = (threadIdx.x >= off) ? sm[threadIdx.x - off] : 0;
    __syncthreads();
    sm[threadIdx.x] += t;
    __syncthreads();
  }
  if (i < N_NODES) rowptr[i + 1] = sm[threadIdx.x];
  if (threadIdx.x == SCAN_BLK - 1) partial[blockIdx.x] = sm[threadIdx.x];
}

__global__ void k_scan2(int* __restrict__ partial) {
  int lane = threadIdx.x;
  int v = (lane < SCAN_GRID) ? partial[lane] : 0;
  #pragma unroll
  for (int off = 1; off < 64; off <<= 1) {
    int t = __shfl_up(v, off);
    if (lane >= off) v += t;
  }
  if (lane < SCAN_GRID) partial[lane] = v;
}

__global__ __launch_bounds__(SCAN_BLK) void k_scan3(int* __restrict__ rowptr,
                                                    const int* __restrict__ partial) {
  int i = blockIdx.x * SCAN_BLK + threadIdx.x;
  if (i == 0) rowptr[0] = 0;
  if (i < N_NODES && blockIdx.x > 0) rowptr[i + 1] += partial[blockIdx.x - 1];
}

__global__ void k_fill(const int* __restrict__ ei, const int* __restrict__ rowptr,
                       int* __restrict__ fill, int* __restrict__ col) {
  int e = blockIdx.x * blockDim.x + threadIdx.x;
  if (e >= E_TOT) return;
  int src, dst;
  if (e < N_EDGES) { src = ei[e]; dst = ei[N_EDGES + e]; }
  else { src = e - N_EDGES; dst = src; }
  int pos = rowptr[dst] + atomicAdd(&fill[dst], 1);
  col[pos] = src;
}

// ---------------- all-layers W -> fp16 hi/lo fragment-order conversion ----------------
struct WPtrs {
  const float* w[4];
  _Float16* h[4];
  _Float16* l[4];
};
__global__ __launch_bounds__(256) void k_wconv_all(WPtrs p) {
  int layer = blockIdx.x >> 6;
  int e = (blockIdx.x & 63) * 256 + threadIdx.x;   // 0..16383
  int k = e >> 7, n = e & 127;
  float v = p.w[layer][e];
  _Float16 h = (_Float16)v;
  _Float16 lo = (_Float16)(v - (float)h);
  int idx = (n >> 4) * 2048 + (k >> 3) * 128 + (n & 15) * 8 + (k & 7);
  p.h[layer][idx] = h;
  p.l[layer][idx] = lo;
}

// ---------------- GEMM via fp16x2 split MFMA + fused alpha dots ----------------
__global__ __launch_bounds__(256) void k_gemm_mfma(const float* __restrict__ X,
                                                   const _Float16* __restrict__ Whf,
                                                   const _Float16* __restrict__ Wlf,
                                                   float* __restrict__ H,
                                                   const float* __restrict__ asrc,
                                                   const float* __restrict__ adst,
                                                   float* __restrict__ alpha_s,
                                                   float* __restrict__ alpha_d) {
  __shared__ __align__(16) _Float16 AhL[8192];   // [w][kgf][r16][8]
  __shared__ __align__(16) _Float16 AlL[8192];
  const int tid = threadIdx.x;
  const int l = tid & 63;
  const int w = tid >> 6;
  const int rowbase = blockIdx.x * 64;

  #pragma unroll
  for (int p = 0; p < 4; ++p) {
    int row = p * 16 + (tid >> 4);
    int k0 = (tid & 15) * 8;
    int grow = rowbase + row;
    float xv[8];
    if (grow < N_NODES) {
      float4 f0 = *reinterpret_cast<const float4*>(&X[(size_t)grow * D + k0]);
      float4 f1 = *reinterpret_cast<const float4*>(&X[(size_t)grow * D + k0 + 4]);
      xv[0] = f0.x; xv[1] = f0.y; xv[2] = f0.z; xv[3] = f0.w;
      xv[4] = f1.x; xv[5] = f1.y; xv[6] = f1.z; xv[7] = f1.w;
    } else {
      #pragma unroll
      for (int j = 0; j < 8; ++j) xv[j] = 0.f;
    }
    f16x8 ah, al;
    #pragma unroll
    for (int j = 0; j < 8; ++j) {
      ah[j] = (_Float16)xv[j];
      al[j] = (_Float16)(xv[j] - (float)ah[j]);
    }
    int idx = (((row >> 4) * 16 + (k0 >> 3)) * 16 + (row & 15)) * 8;
    *reinterpret_cast<f16x8*>(&AhL[idx]) = ah;
    *reinterpret_cast<f16x8*>(&AlL[idx]) = al;
  }
  __syncthreads();

  f32x4 acc[8];
  #pragma unroll
  for (int cc = 0; cc < 8; ++cc) acc[cc] = (f32x4){0.f, 0.f, 0.f, 0.f};

  #pragma unroll
  for (int kt = 0; kt < 4; ++kt) {
    int aidx = w * 2048 + kt * 512 + l * 8;
    f16x8 ah = *reinterpret_cast<const f16x8*>(&AhL[aidx]);
    f16x8 al = *reinterpret_cast<const f16x8*>(&AlL[aidx]);
    #pragma unroll
    for (int cc = 0; cc < 8; ++cc) {
      int bidx = cc * 2048 + kt * 512 + l * 8;
      f16x8 bh = *reinterpret_cast<const f16x8*>(&Whf[bidx]);
      f16x8 bl = *reinterpret_cast<const f16x8*>(&Wlf[bidx]);
      acc[cc] = __builtin_amdgcn_mfma_f32_16x16x32_f16(ah, bh, acc[cc], 0, 0, 0);
      acc[cc] = __builtin_amdgcn_mfma_f32_16x16x32_f16(ah, bl, acc[cc], 0, 0, 0);
      acc[cc] = __builtin_amdgcn_mfma_f32_16x16x32_f16(al, bh, acc[cc], 0, 0, 0);
    }
  }

  const int myn = l & 15;
  const int rg4 = l >> 4;
  float asv[8], adv[8];
  #pragma unroll
  for (int cc = 0; cc < 8; ++cc) {
    asv[cc] = asrc[cc * 16 + myn];
    adv[cc] = adst[cc * 16 + myn];
  }
  #pragma unroll
  for (int reg = 0; reg < 4; ++reg) {
    int grow = rowbase + w * 16 + rg4 * 4 + reg;
    float ps = 0.f, pd = 0.f;
    #pragma unroll
    for (int cc = 0; cc < 8; ++cc) {
      float v = acc[cc][reg];
      ps = fmaf(v, asv[cc], ps);
      pd = fmaf(v, adv[cc], pd);
      if (grow < N_NODES) H[(size_t)grow * D + cc * 16 + myn] = v;
    }
    #pragma unroll
    for (int off = 1; off < 16; off <<= 1) {
      ps += __shfl_xor(ps, off);
      pd += __shfl_xor(pd, off);
    }
    if (grow < N_NODES && myn == 0) {
      alpha_s[grow] = ps;
      alpha_d[grow] = pd;
    }
  }
}

// ---------------- half-split fused agg (layers 1-3): h = blockIdx&1 = feature half ----------------
// Under round-robin block->XCD dispatch, even XCDs touch only H cols [0,64), odd [64,128):
// each XCD's L2 working set halves -> FETCH ~105 MB instead of 192.
__global__ __launch_bounds__(256) void k_agg_half(const float* __restrict__ H,
                                                  const int* __restrict__ rowptr,
                                                  const int* __restrict__ col,
                                                  const float* __restrict__ alpha_s,
                                                  const float* __restrict__ alpha_d,
                                                  const float* __restrict__ bias,
                                                  float* __restrict__ Out) {
  __shared__ float wls[4][MAXDEG];
  __shared__ int cls[4][MAXDEG];
  const int wid = threadIdx.x >> 6;
  const int lane = threadIdx.x & 63;
  const int h = blockIdx.x & 1;
  const int node = (blockIdx.x >> 1) * 4 + wid;
  if (node >= N_NODES) return;
  const int start = rowptr[node], end = rowptr[node + 1];
  const int deg = end - start;
  const float ad = alpha_d[node];

  // pass 1: e into registers + cols into LDS, wave max (full wave)
  float earr[4];
  #pragma unroll
  for (int k = 0; k < 4; ++k) {
    int j0 = lane + k * 64;
    earr[k] = -1e30f;
    if (j0 < deg) {
      int s = col[start + j0];
      float e = alpha_s[s] + ad;
      e = e >= 0.f ? e : NEG_SLOPE * e;
      cls[wid][j0] = s;
      earr[k] = e;
    }
  }
  float m = fmaxf(fmaxf(earr[0], earr[1]), fmaxf(earr[2], earr[3]));
  for (int j0 = MAXDEG + lane; j0 < deg; j0 += 64) {
    int s = col[start + j0];
    float e = alpha_s[s] + ad;
    e = e >= 0.f ? e : NEG_SLOPE * e;
    m = fmaxf(m, e);
  }
  m = wave_max(m);

  // pass 2: weights into LDS, wave sum
  float dsum = 0.f;
  #pragma unroll
  for (int k = 0; k < 4; ++k) {
    int j0 = lane + k * 64;
    if (j0 < deg) {
      float w = expf(earr[k] - m);
      wls[wid][j0] = w;
      dsum += w;
    }
  }
  for (int j0 = MAXDEG + lane; j0 < deg; j0 += 64) {
    int s = col[start + j0];
    float e = alpha_s[s] + ad;
    e = e >= 0.f ? e : NEG_SLOPE * e;
    dsum += expf(e - m);
  }
  dsum = wave_sum(dsum);
  float inv = 1.f / (dsum + 1e-16f);

  // pass 3: 2 edges per instruction (half-wave each), 64-feature half per node
  const int e2 = lane >> 5;          // edge parity
  const int f = lane & 31;           // feature pair within half
  const int fbase = h * 64 + f * 2;
  float2 acc = make_float2(0.f, 0.f);
  const int degc = deg < MAXDEG ? deg : MAXDEG;
  for (int jj = 0; jj < degc; jj += 16) {
    float w[8];
    float2 hv[8];
    #pragma unroll
    for (int u = 0; u < 8; ++u) {
      int idx = jj + u * 2 + e2;
      bool ok = idx < degc;
      int s = ok ? cls[wid][idx] : cls[wid][0];
      w[u] = ok ? wls[wid][idx] : 0.f;
      hv[u] = *reinterpret_cast<const float2*>(&H[(size_t)s * D + fbase]);
    }
    #pragma unroll
    for (int u = 0; u < 8; ++u) {
      acc.x = fmaf(w[u], hv[u].x, acc.x);
      acc.y = fmaf(w[u], hv[u].y, acc.y);
    }
  }
  for (int jj = MAXDEG; jj < deg; jj += 2) {   // cold fallback
    int idx = jj + e2;
    bool ok = idx < deg;
    int s = ok ? col[start + idx] : col[start];
    float e = alpha_s[s] + ad;
    e = e >= 0.f ? e : NEG_SLOPE * e;
    float w = ok ? expf(e - m) : 0.f;
    float2 hv = *reinterpret_cast<const float2*>(&H[(size_t)s * D + fbase]);
    acc.x = fmaf(w, hv.x, acc.x);
    acc.y = fmaf(w, hv.y, acc.y);
  }
  // combine the two edge-parity partials (lane l <-> l^32 share the same features)
  acc.x += __shfl_xor(acc.x, 32);
  acc.y += __shfl_xor(acc.y, 32);

  if (e2 == 0) {
    float2 bv = *reinterpret_cast<const float2*>(&bias[fbase]);
    float ox = fmaxf(acc.x * inv + bv.x, 0.f);
    float oy = fmaxf(acc.y * inv + bv.y, 0.f);
    *reinterpret_cast<float2*>(&Out[(size_t)node * D + fbase]) = make_float2(ox, oy);
  }
}

// ---------------- full-D fused agg (layer 4): + fcW dot -> ynode ----------------
__global__ __launch_bounds__(256) void k_agg_final(const float* __restrict__ H,
                                                   const int* __restrict__ rowptr,
                                                   const int* __restrict__ col,
                                                   const float* __restrict__ alpha_s,
                                                   const float* __restrict__ alpha_d,
                                                   const float* __restrict__ bias,
                                                   const float* __restrict__ fcW,
                                                   float* __restrict__ ynode) {
  __shared__ float wls[4][MAXDEG];
  __shared__ int cls[4][MAXDEG];
  int wid = threadIdx.x >> 6;
  int lane = threadIdx.x & 63;
  int node = blockIdx.x * 4 + wid;
  if (node >= N_NODES) return;
  int start = rowptr[node], end = rowptr[node + 1];
  int deg = end - start;
  float ad = alpha_d[node];

  float earr[4];
  #pragma unroll
  for (int k = 0; k < 4; ++k) {
    int j0 = lane + k * 64;
    earr[k] = -1e30f;
    if (j0 < deg) {
      int s = col[start + j0];
      float e = alpha_s[s] + ad;
      e = e >= 0.f ? e : NEG_SLOPE * e;
      cls[wid][j0] = s;
      earr[k] = e;
    }
  }
  float m = fmaxf(fmaxf(earr[0], earr[1]), fmaxf(earr[2], earr[3]));
  for (int j0 = MAXDEG + lane; j0 < deg; j0 += 64) {
    int s = col[start + j0];
    float e = alpha_s[s] + ad;
    e = e >= 0.f ? e : NEG_SLOPE * e;
    m = fmaxf(m, e);
  }
  m = wave_max(m);

  float dsum = 0.f;
  #pragma unroll
  for (int k = 0; k < 4; ++k) {
    int j0 = lane + k * 64;
    if (j0 < deg) {
      float w = expf(earr[k] - m);
      wls[wid][j0] = w;
      dsum += w;
    }
  }
  for (int j0 = MAXDEG + lane; j0 < deg; j0 += 64) {
    int s = col[start + j0];
    float e = alpha_s[s] + ad;
    e = e >= 0.f ? e : NEG_SLOPE * e;
    dsum += expf(e - m);
  }
  dsum = wave_sum(dsum);
  float inv = 1.f / (dsum + 1e-16f);

  float2 acc = make_float2(0.f, 0.f);
  int degc = deg < MAXDEG ? deg : MAXDEG;
  for (int jj = 0; jj < degc; jj += 8) {
    float w[8];
    float2 hv[8];
    #pragma unroll
    for (int u = 0; u < 8; ++u) {
      int idx = jj + u;
      bool ok = idx < degc;
      int s = ok ? cls[wid][idx] : cls[wid][0];
      w[u] = ok ? wls[wid][idx] : 0.f;
      hv[u] = *reinterpret_cast<const float2*>(&H[(size_t)s * D + lane * 2]);
    }
    #pragma unroll
    for (int u = 0; u < 8; ++u) {
      acc.x = fmaf(w[u], hv[u].x, acc.x);
      acc.y = fmaf(w[u], hv[u].y, acc.y);
    }
  }
  for (int jj = MAXDEG; jj < deg; ++jj) {
    int s = col[start + jj];
    float e = alpha_s[s] + ad;
    e = e >= 0.f ? e : NEG_SLOPE * e;
    float w = expf(e - m);
    float2 hv = *reinterpret_cast<const float2*>(&H[(size_t)s * D + lane * 2]);
    acc.x = fmaf(w, hv.x, acc.x);
    acc.y = fmaf(w, hv.y, acc.y);
  }

  float2 bv = *reinterpret_cast<const float2*>(&bias[lane * 2]);
  float ox = fmaxf(acc.x * inv + bv.x, 0.f);
  float oy = fmaxf(acc.y * inv + bv.y, 0.f);
  float2 wv = *reinterpret_cast<const float2*>(&fcW[lane * 2]);
  float y = wave_sum(ox * wv.x + oy * wv.y);
  if (lane == 0) ynode[node] = y;
}

// ---------------- finalize: per-graph mean of ynode + bias ----------------
__global__ __launch_bounds__(256) void k_final(const float* __restrict__ ynode,
                                               const int* __restrict__ batch,
                                               const float* __restrict__ fcb,
                                               float* __restrict__ out) {
  __shared__ float sm[256];
  int b = blockIdx.x;
  int tid = threadIdx.x;
  int lo = 0, hi = N_NODES;
  while (lo < hi) { int mid = (lo + hi) >> 1; if (batch[mid] < b) lo = mid + 1; else hi = mid; }
  int s0 = lo;
  lo = 0; hi = N_NODES;
  while (lo < hi) { int mid = (lo + hi) >> 1; if (batch[mid] < b + 1) lo = mid + 1; else hi = mid; }
  int s1 = lo;
  float sum = 0.f;
  for (int n = s0 + tid; n < s1; n += 256) sum += ynode[n];
  sm[tid] = sum;
  __syncthreads();
  #pragma unroll
  for (int off = 128; off > 0; off >>= 1) {
    if (tid < off) sm[tid] += sm[tid + off];
    __syncthreads();
  }
  if (tid == 0) out[b] = sm[0] / fmaxf((float)(s1 - s0), 1.f) + fcb[0];
}

extern "C" void kernel_launch(void* const* d_in, const int* in_sizes, int n_in,
                              void* d_out, int out_size, void* d_ws, size_t ws_size,
                              hipStream_t stream) {
  const float* x = (const float*)d_in[0];
  const int* ei = (const int*)d_in[1];
  const int* batch = (const int*)d_in[2];
  const float* W[4]   = {(const float*)d_in[3], (const float*)d_in[7],
                         (const float*)d_in[11], (const float*)d_in[15]};
  const float* asr[4] = {(const float*)d_in[4], (const float*)d_in[8],
                         (const float*)d_in[12], (const float*)d_in[16]};
  const float* adt[4] = {(const float*)d_in[5], (const float*)d_in[9],
                         (const float*)d_in[13], (const float*)d_in[17]};
  const float* bs[4]  = {(const float*)d_in[6], (const float*)d_in[10],
                         (const float*)d_in[14], (const float*)d_in[18]};
  const float* fcW = (const float*)d_in[19];
  const float* fcb = (const float*)d_in[20];
  float* out = (float*)d_out;

  char* ws = (char*)d_ws;
  size_t off = 0;
  float* hA = (float*)(ws + off); off += (size_t)N_NODES * D * 4;
  float* hB = (float*)(ws + off); off += (size_t)N_NODES * D * 4;
  float* alpha_s = (float*)(ws + off); off += (size_t)N_NODES * 4;
  float* alpha_d = (float*)(ws + off); off += (size_t)N_NODES * 4;
  int* cnt  = (int*)(ws + off); off += (size_t)N_NODES * 4;
  int* fill = (int*)(ws + off); off += (size_t)N_NODES * 4;
  int* rowptr = (int*)(ws + off); off += (size_t)(N_NODES + 1) * 4 + 12;
  int* col = (int*)(ws + off); off += (size_t)E_TOT * 4;
  float* ynode = (float*)(ws + off); off += (size_t)N_NODES * 4;
  int* partial = (int*)(ws + off); off += ((size_t)SCAN_GRID * 4 + 15) & ~15ull;
  _Float16* Whf[4];
  _Float16* Wlf[4];
  for (int lyr = 0; lyr < 4; ++lyr) {
    Whf[lyr] = (_Float16*)(ws + off); off += (size_t)D * D * 2;
    Wlf[lyr] = (_Float16*)(ws + off); off += (size_t)D * D * 2;
  }
  (void)ws_size; (void)in_sizes; (void)n_in; (void)out_size;

  hipMemsetAsync(cnt, 0, (size_t)N_NODES * 4 * 2, stream);  // zero cnt + fill
  WPtrs wp;
  for (int lyr = 0; lyr < 4; ++lyr) { wp.w[lyr] = W[lyr]; wp.h[lyr] = Whf[lyr]; wp.l[lyr] = Wlf[lyr]; }
  k_wconv_all<<<256, 256, 0, stream>>>(wp);
  int eb = (E_TOT + 255) / 256;
  k_count<<<eb, 256, 0, stream>>>(ei, cnt);
  k_scan1<<<SCAN_GRID, SCAN_BLK, 0, stream>>>(cnt, rowptr, partial);
  k_scan2<<<1, 64, 0, stream>>>(partial);
  k_scan3<<<SCAN_GRID, SCAN_BLK, 0, stream>>>(rowptr, partial);
  k_fill<<<eb, 256, 0, stream>>>(ei, rowptr, fill, col);

  const float* in = x;
  for (int l = 0; l < 4; ++l) {
    k_gemm_mfma<<<(N_NODES + 63) / 64, 256, 0, stream>>>(in, Whf[l], Wlf[l], hA,
                                                         asr[l], adt[l], alpha_s, alpha_d);
    if (l < 3) {
      k_agg_half<<<2 * ((N_NODES + 3) / 4), 256, 0, stream>>>(hA, rowptr, col,
                                                              alpha_s, alpha_d, bs[l], hB);
    } else {
      k_agg_final<<<(N_NODES + 3) / 4, 256, 0, stream>>>(hA, rowptr, col, alpha_s,
                                                         alpha_d, bs[l], fcW, ynode);
    }
    in = hB;
  }
  k_final<<<N_GRAPHS, 256, 0, stream>>>(ynode, batch, fcb, out);
}

// Round 13
// 415.288 us; speedup vs baseline: 1.0278x; 1.0278x over previous
//
#include <hip/hip_runtime.h>

#define N_NODES 50000
#define N_EDGES 800000
#define E_TOT (N_EDGES + N_NODES)
#define D 128
#define N_GRAPHS 64
#define NEG_SLOPE 0.2f
#define MAXDEG 256
#define SCAN_BLK 1024
#define SCAN_GRID ((N_NODES + SCAN_BLK - 1) / SCAN_BLK)   // 49

typedef _Float16 f16x8 __attribute__((ext_vector_type(8)));
typedef float f32x4 __attribute__((ext_vector_type(4)));

__device__ __forceinline__ float wave_max(float v) {
  #pragma unroll
  for (int off = 32; off > 0; off >>= 1) v = fmaxf(v, __shfl_xor(v, off));
  return v;
}
__device__ __forceinline__ float wave_sum(float v) {
  #pragma unroll
  for (int off = 32; off > 0; off >>= 1) v += __shfl_xor(v, off);
  return v;
}

// ---------------- CSR build ----------------
__global__ void k_count(const int* __restrict__ ei, int* __restrict__ cnt) {
  int e = blockIdx.x * blockDim.x + threadIdx.x;
  if (e >= E_TOT) return;
  int dst = (e < N_EDGES) ? ei[N_EDGES + e] : (e - N_EDGES);
  atomicAdd(&cnt[dst], 1);
}

__global__ __launch_bounds__(SCAN_BLK) void k_scan1(const int* __restrict__ cnt,
                                                    int* __restrict__ rowptr,
                                                    int* __restrict__ partial) {
  __shared__ int sm[SCAN_BLK];
  int i = blockIdx.x * SCAN_BLK + threadIdx.x;
  int v = (i < N_NODES) ? cnt[i] : 0;
  sm[threadIdx.x] = v;
  __syncthreads();
  #pragma unroll
  for (int off = 1; off < SCAN_BLK; off <<= 1) {
    int t = (threadIdx.x >= off) ? sm[threadIdx.x - off] : 0;
    __syncthreads();
    sm[threadIdx.x] += t;
    __syncthreads();
  }
  if (i < N_NODES) rowptr[i + 1] = sm[threadIdx.x];
  if (threadIdx.x == SCAN_BLK - 1) partial[blockIdx.x] = sm[threadIdx.x];
}

__global__ void k_scan2(int* __restrict__ partial) {
  int lane = threadIdx.x;
  int v = (lane < SCAN_GRID) ? partial[lane] : 0;
  #pragma unroll
  for (int off = 1; off < 64; off <<= 1) {
    int t = __shfl_up(v, off);
    if (lane >= off) v += t;
  }
  if (lane < SCAN_GRID) partial[lane] = v;
}

__global__ __launch_bounds__(SCAN_BLK) void k_scan3(int* __restrict__ rowptr,
                                                    const int* __restrict__ partial) {
  int i = blockIdx.x * SCAN_BLK + threadIdx.x;
  if (i == 0) rowptr[0] = 0;
  if (i < N_NODES && blockIdx.x > 0) rowptr[i + 1] += partial[blockIdx.x - 1];
}

__global__ void k_fill(const int* __restrict__ ei, const int* __restrict__ rowptr,
                       int* __restrict__ fill, int* __restrict__ col) {
  int e = blockIdx.x * blockDim.x + threadIdx.x;
  if (e >= E_TOT) return;
  int src, dst;
  if (e < N_EDGES) { src = ei[e]; dst = ei[N_EDGES + e]; }
  else { src = e - N_EDGES; dst = src; }
  int pos = rowptr[dst] + atomicAdd(&fill[dst], 1);
  col[pos] = src;
}

// ---------------- all-layers W -> fp16 hi/lo fragment-order conversion ----------------
struct WPtrs {
  const float* w[4];
  _Float16* h[4];
  _Float16* l[4];
};
__global__ __launch_bounds__(256) void k_wconv_all(WPtrs p) {
  int layer = blockIdx.x >> 6;
  int e = (blockIdx.x & 63) * 256 + threadIdx.x;   // 0..16383
  int k = e >> 7, n = e & 127;
  float v = p.w[layer][e];
  _Float16 h = (_Float16)v;
  _Float16 lo = (_Float16)(v - (float)h);
  int idx = (n >> 4) * 2048 + (k >> 3) * 128 + (n & 15) * 8 + (k & 7);
  p.h[layer][idx] = h;
  p.l[layer][idx] = lo;
}

// ---------------- GEMM via fp16x2 split MFMA + fused alpha dots ----------------
__global__ __launch_bounds__(256) void k_gemm_mfma(const float* __restrict__ X,
                                                   const _Float16* __restrict__ Whf,
                                                   const _Float16* __restrict__ Wlf,
                                                   float* __restrict__ H,
                                                   const float* __restrict__ asrc,
                                                   const float* __restrict__ adst,
                                                   float* __restrict__ alpha_s,
                                                   float* __restrict__ alpha_d) {
  __shared__ __align__(16) _Float16 AhL[8192];   // [w][kgf][r16][8]
  __shared__ __align__(16) _Float16 AlL[8192];
  const int tid = threadIdx.x;
  const int l = tid & 63;
  const int w = tid >> 6;
  const int rowbase = blockIdx.x * 64;

  #pragma unroll
  for (int p = 0; p < 4; ++p) {
    int row = p * 16 + (tid >> 4);
    int k0 = (tid & 15) * 8;
    int grow = rowbase + row;
    float xv[8];
    if (grow < N_NODES) {
      float4 f0 = *reinterpret_cast<const float4*>(&X[(size_t)grow * D + k0]);
      float4 f1 = *reinterpret_cast<const float4*>(&X[(size_t)grow * D + k0 + 4]);
      xv[0] = f0.x; xv[1] = f0.y; xv[2] = f0.z; xv[3] = f0.w;
      xv[4] = f1.x; xv[5] = f1.y; xv[6] = f1.z; xv[7] = f1.w;
    } else {
      #pragma unroll
      for (int j = 0; j < 8; ++j) xv[j] = 0.f;
    }
    f16x8 ah, al;
    #pragma unroll
    for (int j = 0; j < 8; ++j) {
      ah[j] = (_Float16)xv[j];
      al[j] = (_Float16)(xv[j] - (float)ah[j]);
    }
    int idx = (((row >> 4) * 16 + (k0 >> 3)) * 16 + (row & 15)) * 8;
    *reinterpret_cast<f16x8*>(&AhL[idx]) = ah;
    *reinterpret_cast<f16x8*>(&AlL[idx]) = al;
  }
  __syncthreads();

  f32x4 acc[8];
  #pragma unroll
  for (int cc = 0; cc < 8; ++cc) acc[cc] = (f32x4){0.f, 0.f, 0.f, 0.f};

  #pragma unroll
  for (int kt = 0; kt < 4; ++kt) {
    int aidx = w * 2048 + kt * 512 + l * 8;
    f16x8 ah = *reinterpret_cast<const f16x8*>(&AhL[aidx]);
    f16x8 al = *reinterpret_cast<const f16x8*>(&AlL[aidx]);
    #pragma unroll
    for (int cc = 0; cc < 8; ++cc) {
      int bidx = cc * 2048 + kt * 512 + l * 8;
      f16x8 bh = *reinterpret_cast<const f16x8*>(&Whf[bidx]);
      f16x8 bl = *reinterpret_cast<const f16x8*>(&Wlf[bidx]);
      acc[cc] = __builtin_amdgcn_mfma_f32_16x16x32_f16(ah, bh, acc[cc], 0, 0, 0);
      acc[cc] = __builtin_amdgcn_mfma_f32_16x16x32_f16(ah, bl, acc[cc], 0, 0, 0);
      acc[cc] = __builtin_amdgcn_mfma_f32_16x16x32_f16(al, bh, acc[cc], 0, 0, 0);
    }
  }

  const int myn = l & 15;
  const int rg4 = l >> 4;
  float asv[8], adv[8];
  #pragma unroll
  for (int cc = 0; cc < 8; ++cc) {
    asv[cc] = asrc[cc * 16 + myn];
    adv[cc] = adst[cc * 16 + myn];
  }
  #pragma unroll
  for (int reg = 0; reg < 4; ++reg) {
    int grow = rowbase + w * 16 + rg4 * 4 + reg;
    float ps = 0.f, pd = 0.f;
    #pragma unroll
    for (int cc = 0; cc < 8; ++cc) {
      float v = acc[cc][reg];
      ps = fmaf(v, asv[cc], ps);
      pd = fmaf(v, adv[cc], pd);
      if (grow < N_NODES) H[(size_t)grow * D + cc * 16 + myn] = v;
    }
    #pragma unroll
    for (int off = 1; off < 16; off <<= 1) {
      ps += __shfl_xor(ps, off);
      pd += __shfl_xor(pd, off);
    }
    if (grow < N_NODES && myn == 0) {
      alpha_s[grow] = ps;
      alpha_d[grow] = pd;
    }
  }
}

// ---------------- fused segment softmax + aggregate + bias + relu ----------------
template <int FINAL>
__global__ __launch_bounds__(256) void k_agg(const float* __restrict__ H,
                                             const int* __restrict__ rowptr,
                                             const int* __restrict__ col,
                                             const float* __restrict__ alpha_s,
                                             const float* __restrict__ alpha_d,
                                             const float* __restrict__ bias,
                                             float* __restrict__ Out,
                                             const float* __restrict__ fcW,
                                             float* __restrict__ ynode) {
  __shared__ float wls[4][MAXDEG];
  __shared__ int cls[4][MAXDEG];
  int wid = threadIdx.x >> 6;
  int lane = threadIdx.x & 63;
  int node = blockIdx.x * 4 + wid;
  if (node >= N_NODES) return;
  int start = rowptr[node], end = rowptr[node + 1];
  int deg = end - start;
  float ad = alpha_d[node];

  // pass 1: e into registers + cols into LDS, wave max
  float earr[4];
  float m = -1e30f;
  #pragma unroll
  for (int k = 0; k < 4; ++k) {
    int j0 = lane + k * 64;
    earr[k] = -1e30f;
    if (j0 < deg) {
      int s = col[start + j0];
      float e = alpha_s[s] + ad;
      e = e >= 0.f ? e : NEG_SLOPE * e;
      cls[wid][j0] = s;
      earr[k] = e;
    }
  }
  m = fmaxf(fmaxf(earr[0], earr[1]), fmaxf(earr[2], earr[3]));
  for (int j0 = MAXDEG + lane; j0 < deg; j0 += 64) {
    int s = col[start + j0];
    float e = alpha_s[s] + ad;
    e = e >= 0.f ? e : NEG_SLOPE * e;
    m = fmaxf(m, e);
  }
  m = wave_max(m);

  // pass 2: weights into LDS, wave sum
  float dsum = 0.f;
  #pragma unroll
  for (int k = 0; k < 4; ++k) {
    int j0 = lane + k * 64;
    if (j0 < deg) {
      float w = expf(earr[k] - m);
      wls[wid][j0] = w;
      dsum += w;
    }
  }
  for (int j0 = MAXDEG + lane; j0 < deg; j0 += 64) {
    int s = col[start + j0];
    float e = alpha_s[s] + ad;
    e = e >= 0.f ? e : NEG_SLOPE * e;
    dsum += expf(e - m);
  }
  dsum = wave_sum(dsum);
  float inv = 1.f / (dsum + 1e-16f);

  // pass 3: gather in masked batches of 8 (8 loads in flight, no serial tail)
  float2 acc = make_float2(0.f, 0.f);
  int degc = deg < MAXDEG ? deg : MAXDEG;
  for (int jj = 0; jj < degc; jj += 8) {
    float w[8];
    float2 hv[8];
    #pragma unroll
    for (int u = 0; u < 8; ++u) {
      int idx = jj + u;
      bool ok = idx < degc;
      int s = ok ? cls[wid][idx] : cls[wid][0];
      w[u] = ok ? wls[wid][idx] : 0.f;
      hv[u] = *reinterpret_cast<const float2*>(&H[(size_t)s * D + lane * 2]);
    }
    #pragma unroll
    for (int u = 0; u < 8; ++u) {
      acc.x = fmaf(w[u], hv[u].x, acc.x);
      acc.y = fmaf(w[u], hv[u].y, acc.y);
    }
  }
  for (int jj = MAXDEG; jj < deg; ++jj) {   // cold fallback
    int s = col[start + jj];
    float e = alpha_s[s] + ad;
    e = e >= 0.f ? e : NEG_SLOPE * e;
    float w = expf(e - m);
    float2 hv = *reinterpret_cast<const float2*>(&H[(size_t)s * D + lane * 2]);
    acc.x = fmaf(w, hv.x, acc.x);
    acc.y = fmaf(w, hv.y, acc.y);
  }

  float2 bv = *reinterpret_cast<const float2*>(&bias[lane * 2]);
  float ox = fmaxf(acc.x * inv + bv.x, 0.f);
  float oy = fmaxf(acc.y * inv + bv.y, 0.f);
  if (FINAL) {
    float2 wv = *reinterpret_cast<const float2*>(&fcW[lane * 2]);
    float y = wave_sum(ox * wv.x + oy * wv.y);
    if (lane == 0) ynode[node] = y;
  } else {
    *reinterpret_cast<float2*>(&Out[(size_t)node * D + lane * 2]) = make_float2(ox, oy);
  }
}

// ---------------- finalize: per-graph mean of ynode + bias ----------------
__global__ __launch_bounds__(256) void k_final(const float* __restrict__ ynode,
                                               const int* __restrict__ batch,
                                               const float* __restrict__ fcb,
                                               float* __restrict__ out) {
  __shared__ float sm[256];
  int b = blockIdx.x;
  int tid = threadIdx.x;
  int lo = 0, hi = N_NODES;
  while (lo < hi) { int mid = (lo + hi) >> 1; if (batch[mid] < b) lo = mid + 1; else hi = mid; }
  int s0 = lo;
  lo = 0; hi = N_NODES;
  while (lo < hi) { int mid = (lo + hi) >> 1; if (batch[mid] < b + 1) lo = mid + 1; else hi = mid; }
  int s1 = lo;
  float sum = 0.f;
  for (int n = s0 + tid; n < s1; n += 256) sum += ynode[n];
  sm[tid] = sum;
  __syncthreads();
  #pragma unroll
  for (int off = 128; off > 0; off >>= 1) {
    if (tid < off) sm[tid] += sm[tid + off];
    __syncthreads();
  }
  if (tid == 0) out[b] = sm[0] / fmaxf((float)(s1 - s0), 1.f) + fcb[0];
}

extern "C" void kernel_launch(void* const* d_in, const int* in_sizes, int n_in,
                              void* d_out, int out_size, void* d_ws, size_t ws_size,
                              hipStream_t stream) {
  const float* x = (const float*)d_in[0];
  const int* ei = (const int*)d_in[1];
  const int* batch = (const int*)d_in[2];
  const float* W[4]   = {(const float*)d_in[3], (const float*)d_in[7],
                         (const float*)d_in[11], (const float*)d_in[15]};
  const float* asr[4] = {(const float*)d_in[4], (const float*)d_in[8],
                         (const float*)d_in[12], (const float*)d_in[16]};
  const float* adt[4] = {(const float*)d_in[5], (const float*)d_in[9],
                         (const float*)d_in[13], (const float*)d_in[17]};
  const float* bs[4]  = {(const float*)d_in[6], (const float*)d_in[10],
                         (const float*)d_in[14], (const float*)d_in[18]};
  const float* fcW = (const float*)d_in[19];
  const float* fcb = (const float*)d_in[20];
  float* out = (float*)d_out;

  char* ws = (char*)d_ws;
  size_t off = 0;
  float* hA = (float*)(ws + off); off += (size_t)N_NODES * D * 4;
  float* hB = (float*)(ws + off); off += (size_t)N_NODES * D * 4;
  float* alpha_s = (float*)(ws + off); off += (size_t)N_NODES * 4;
  float* alpha_d = (float*)(ws + off); off += (size_t)N_NODES * 4;
  int* cnt  = (int*)(ws + off); off += (size_t)N_NODES * 4;
  int* fill = (int*)(ws + off); off += (size_t)N_NODES * 4;
  int* rowptr = (int*)(ws + off); off += (size_t)(N_NODES + 1) * 4 + 12;
  int* col = (int*)(ws + off); off += (size_t)E_TOT * 4;
  float* ynode = (float*)(ws + off); off += (size_t)N_NODES * 4;
  int* partial = (int*)(ws + off); off += ((size_t)SCAN_GRID * 4 + 15) & ~15ull;
  _Float16* Whf[4];
  _Float16* Wlf[4];
  for (int lyr = 0; lyr < 4; ++lyr) {
    Whf[lyr] = (_Float16*)(ws + off); off += (size_t)D * D * 2;
    Wlf[lyr] = (_Float16*)(ws + off); off += (size_t)D * D * 2;
  }
  (void)ws_size; (void)in_sizes; (void)n_in; (void)out_size;

  hipMemsetAsync(cnt, 0, (size_t)N_NODES * 4 * 2, stream);  // zero cnt + fill
  WPtrs wp;
  for (int lyr = 0; lyr < 4; ++lyr) { wp.w[lyr] = W[lyr]; wp.h[lyr] = Whf[lyr]; wp.l[lyr] = Wlf[lyr]; }
  k_wconv_all<<<256, 256, 0, stream>>>(wp);
  int eb = (E_TOT + 255) / 256;
  k_count<<<eb, 256, 0, stream>>>(ei, cnt);
  k_scan1<<<SCAN_GRID, SCAN_BLK, 0, stream>>>(cnt, rowptr, partial);
  k_scan2<<<1, 64, 0, stream>>>(partial);
  k_scan3<<<SCAN_GRID, SCAN_BLK, 0, stream>>>(rowptr, partial);
  k_fill<<<eb, 256, 0, stream>>>(ei, rowptr, fill, col);

  const float* in = x;
  for (int l = 0; l < 4; ++l) {
    k_gemm_mfma<<<(N_NODES + 63) / 64, 256, 0, stream>>>(in, Whf[l], Wlf[l], hA,
                                                         asr[l], adt[l], alpha_s, alpha_d);
    if (l < 3) {
      k_agg<0><<<(N_NODES + 3) / 4, 256, 0, stream>>>(hA, rowptr, col, alpha_s, alpha_d,
                                                      bs[l], hB, nullptr, nullptr);
    } else {
      k_agg<1><<<(N_NODES + 3) / 4, 256, 0, stream>>>(hA, rowptr, col, alpha_s, alpha_d,
                                                      bs[l], nullptr, fcW, ynode);
    }
    in = hB;
  }
  k_final<<<N_GRAPHS, 256, 0, stream>>>(ynode, batch, fcb, out);
}

// Round 14
// 345.106 us; speedup vs baseline: 1.2368x; 1.2034x over previous
//
#include <hip/hip_runtime.h>

#define N_NODES 50000
#define N_EDGES 800000
#define E_TOT (N_EDGES + N_NODES)
#define D 128
#define N_GRAPHS 64
#define NEG_SLOPE 0.2f
#define MAXDEG 256
#define SCAN_BLK 1024
#define SCAN_GRID ((N_NODES + SCAN_BLK - 1) / SCAN_BLK)   // 49

typedef _Float16 f16x8 __attribute__((ext_vector_type(8)));
typedef _Float16 f16x2 __attribute__((ext_vector_type(2)));
typedef float f32x4 __attribute__((ext_vector_type(4)));

__device__ __forceinline__ float wave_max(float v) {
  #pragma unroll
  for (int off = 32; off > 0; off >>= 1) v = fmaxf(v, __shfl_xor(v, off));
  return v;
}
__device__ __forceinline__ float wave_sum(float v) {
  #pragma unroll
  for (int off = 32; off > 0; off >>= 1) v += __shfl_xor(v, off);
  return v;
}

// ---------------- CSR build ----------------
__global__ void k_count(const int* __restrict__ ei, int* __restrict__ cnt) {
  int e = blockIdx.x * blockDim.x + threadIdx.x;
  if (e >= E_TOT) return;
  int dst = (e < N_EDGES) ? ei[N_EDGES + e] : (e - N_EDGES);
  atomicAdd(&cnt[dst], 1);
}

__global__ __launch_bounds__(SCAN_BLK) void k_scan1(const int* __restrict__ cnt,
                                                    int* __restrict__ rowptr,
                                                    int* __restrict__ partial) {
  __shared__ int sm[SCAN_BLK];
  int i = blockIdx.x * SCAN_BLK + threadIdx.x;
  int v = (i < N_NODES) ? cnt[i] : 0;
  sm[threadIdx.x] = v;
  __syncthreads();
  #pragma unroll
  for (int off = 1; off < SCAN_BLK; off <<= 1) {
    int t = (threadIdx.x >= off) ? sm[threadIdx.x - off] : 0;
    __syncthreads();
    sm[threadIdx.x] += t;
    __syncthreads();
  }
  if (i < N_NODES) rowptr[i + 1] = sm[threadIdx.x];
  if (threadIdx.x == SCAN_BLK - 1) partial[blockIdx.x] = sm[threadIdx.x];
}

__global__ void k_scan2(int* __restrict__ partial) {
  int lane = threadIdx.x;
  int v = (lane < SCAN_GRID) ? partial[lane] : 0;
  #pragma unroll
  for (int off = 1; off < 64; off <<= 1) {
    int t = __shfl_up(v, off);
    if (lane >= off) v += t;
  }
  if (lane < SCAN_GRID) partial[lane] = v;
}

__global__ __launch_bounds__(SCAN_BLK) void k_scan3(int* __restrict__ rowptr,
                                                    const int* __restrict__ partial) {
  int i = blockIdx.x * SCAN_BLK + threadIdx.x;
  if (i == 0) rowptr[0] = 0;
  if (i < N_NODES && blockIdx.x > 0) rowptr[i + 1] += partial[blockIdx.x - 1];
}

__global__ void k_fill(const int* __restrict__ ei, const int* __restrict__ rowptr,
                       int* __restrict__ fill, int* __restrict__ col) {
  int e = blockIdx.x * blockDim.x + threadIdx.x;
  if (e >= E_TOT) return;
  int src, dst;
  if (e < N_EDGES) { src = ei[e]; dst = ei[N_EDGES + e]; }
  else { src = e - N_EDGES; dst = src; }
  int pos = rowptr[dst] + atomicAdd(&fill[dst], 1);
  col[pos] = src;
}

// ---------------- all-layers W -> fp16 hi/lo fragment-order conversion ----------------
struct WPtrs {
  const float* w[4];
  _Float16* h[4];
  _Float16* l[4];
};
__global__ __launch_bounds__(256) void k_wconv_all(WPtrs p) {
  int layer = blockIdx.x >> 6;
  int e = (blockIdx.x & 63) * 256 + threadIdx.x;   // 0..16383
  int k = e >> 7, n = e & 127;
  float v = p.w[layer][e];
  _Float16 h = (_Float16)v;
  _Float16 lo = (_Float16)(v - (float)h);
  int idx = (n >> 4) * 2048 + (k >> 3) * 128 + (n & 15) * 8 + (k & 7);
  p.h[layer][idx] = h;
  p.l[layer][idx] = lo;
}

// ---------------- GEMM via fp16x2 split MFMA + fused alpha dots + fp16 gather copy ----------------
__global__ __launch_bounds__(256) void k_gemm_mfma(const float* __restrict__ X,
                                                   const _Float16* __restrict__ Whf,
                                                   const _Float16* __restrict__ Wlf,
                                                   float* __restrict__ H,
                                                   _Float16* __restrict__ Hh,
                                                   const float* __restrict__ asrc,
                                                   const float* __restrict__ adst,
                                                   float* __restrict__ alpha_s,
                                                   float* __restrict__ alpha_d) {
  __shared__ __align__(16) _Float16 AhL[8192];   // [w][kgf][r16][8]
  __shared__ __align__(16) _Float16 AlL[8192];
  const int tid = threadIdx.x;
  const int l = tid & 63;
  const int w = tid >> 6;
  const int rowbase = blockIdx.x * 64;

  #pragma unroll
  for (int p = 0; p < 4; ++p) {
    int row = p * 16 + (tid >> 4);
    int k0 = (tid & 15) * 8;
    int grow = rowbase + row;
    float xv[8];
    if (grow < N_NODES) {
      float4 f0 = *reinterpret_cast<const float4*>(&X[(size_t)grow * D + k0]);
      float4 f1 = *reinterpret_cast<const float4*>(&X[(size_t)grow * D + k0 + 4]);
      xv[0] = f0.x; xv[1] = f0.y; xv[2] = f0.z; xv[3] = f0.w;
      xv[4] = f1.x; xv[5] = f1.y; xv[6] = f1.z; xv[7] = f1.w;
    } else {
      #pragma unroll
      for (int j = 0; j < 8; ++j) xv[j] = 0.f;
    }
    f16x8 ah, al;
    #pragma unroll
    for (int j = 0; j < 8; ++j) {
      ah[j] = (_Float16)xv[j];
      al[j] = (_Float16)(xv[j] - (float)ah[j]);
    }
    int idx = (((row >> 4) * 16 + (k0 >> 3)) * 16 + (row & 15)) * 8;
    *reinterpret_cast<f16x8*>(&AhL[idx]) = ah;
    *reinterpret_cast<f16x8*>(&AlL[idx]) = al;
  }
  __syncthreads();

  f32x4 acc[8];
  #pragma unroll
  for (int cc = 0; cc < 8; ++cc) acc[cc] = (f32x4){0.f, 0.f, 0.f, 0.f};

  #pragma unroll
  for (int kt = 0; kt < 4; ++kt) {
    int aidx = w * 2048 + kt * 512 + l * 8;
    f16x8 ah = *reinterpret_cast<const f16x8*>(&AhL[aidx]);
    f16x8 al = *reinterpret_cast<const f16x8*>(&AlL[aidx]);
    #pragma unroll
    for (int cc = 0; cc < 8; ++cc) {
      int bidx = cc * 2048 + kt * 512 + l * 8;
      f16x8 bh = *reinterpret_cast<const f16x8*>(&Whf[bidx]);
      f16x8 bl = *reinterpret_cast<const f16x8*>(&Wlf[bidx]);
      acc[cc] = __builtin_amdgcn_mfma_f32_16x16x32_f16(ah, bh, acc[cc], 0, 0, 0);
      acc[cc] = __builtin_amdgcn_mfma_f32_16x16x32_f16(ah, bl, acc[cc], 0, 0, 0);
      acc[cc] = __builtin_amdgcn_mfma_f32_16x16x32_f16(al, bh, acc[cc], 0, 0, 0);
    }
  }

  const int myn = l & 15;
  const int rg4 = l >> 4;
  float asv[8], adv[8];
  #pragma unroll
  for (int cc = 0; cc < 8; ++cc) {
    asv[cc] = asrc[cc * 16 + myn];
    adv[cc] = adst[cc * 16 + myn];
  }
  #pragma unroll
  for (int reg = 0; reg < 4; ++reg) {
    int grow = rowbase + w * 16 + rg4 * 4 + reg;
    float ps = 0.f, pd = 0.f;
    #pragma unroll
    for (int cc = 0; cc < 8; ++cc) {
      float v = acc[cc][reg];
      ps = fmaf(v, asv[cc], ps);
      pd = fmaf(v, adv[cc], pd);
      if (grow < N_NODES) {
        H[(size_t)grow * D + cc * 16 + myn] = v;
        Hh[(size_t)grow * D + cc * 16 + myn] = (_Float16)v;
      }
    }
    #pragma unroll
    for (int off = 1; off < 16; off <<= 1) {
      ps += __shfl_xor(ps, off);
      pd += __shfl_xor(pd, off);
    }
    if (grow < N_NODES && myn == 0) {
      alpha_s[grow] = ps;
      alpha_d[grow] = pd;
    }
  }
}

// ---------------- fused segment softmax + aggregate (fp16 gather) + bias + relu ----------------
template <int FINAL>
__global__ __launch_bounds__(256) void k_agg(const _Float16* __restrict__ Hh,
                                             const int* __restrict__ rowptr,
                                             const int* __restrict__ col,
                                             const float* __restrict__ alpha_s,
                                             const float* __restrict__ alpha_d,
                                             const float* __restrict__ bias,
                                             float* __restrict__ Out,
                                             const float* __restrict__ fcW,
                                             float* __restrict__ ynode) {
  __shared__ float wls[4][MAXDEG];
  __shared__ int cls[4][MAXDEG];
  int wid = threadIdx.x >> 6;
  int lane = threadIdx.x & 63;
  int node = blockIdx.x * 4 + wid;
  if (node >= N_NODES) return;
  int start = rowptr[node], end = rowptr[node + 1];
  int deg = end - start;
  float ad = alpha_d[node];

  // pass 1: e into registers + cols into LDS, wave max
  float earr[4];
  float m = -1e30f;
  #pragma unroll
  for (int k = 0; k < 4; ++k) {
    int j0 = lane + k * 64;
    earr[k] = -1e30f;
    if (j0 < deg) {
      int s = col[start + j0];
      float e = alpha_s[s] + ad;
      e = e >= 0.f ? e : NEG_SLOPE * e;
      cls[wid][j0] = s;
      earr[k] = e;
    }
  }
  m = fmaxf(fmaxf(earr[0], earr[1]), fmaxf(earr[2], earr[3]));
  for (int j0 = MAXDEG + lane; j0 < deg; j0 += 64) {
    int s = col[start + j0];
    float e = alpha_s[s] + ad;
    e = e >= 0.f ? e : NEG_SLOPE * e;
    m = fmaxf(m, e);
  }
  m = wave_max(m);

  // pass 2: weights into LDS, wave sum
  float dsum = 0.f;
  #pragma unroll
  for (int k = 0; k < 4; ++k) {
    int j0 = lane + k * 64;
    if (j0 < deg) {
      float w = expf(earr[k] - m);
      wls[wid][j0] = w;
      dsum += w;
    }
  }
  for (int j0 = MAXDEG + lane; j0 < deg; j0 += 64) {
    int s = col[start + j0];
    float e = alpha_s[s] + ad;
    e = e >= 0.f ? e : NEG_SLOPE * e;
    dsum += expf(e - m);
  }
  dsum = wave_sum(dsum);
  float inv = 1.f / (dsum + 1e-16f);

  // pass 3: fp16 gather in masked batches of 8 (8 loads in flight)
  float2 acc = make_float2(0.f, 0.f);
  int degc = deg < MAXDEG ? deg : MAXDEG;
  for (int jj = 0; jj < degc; jj += 8) {
    float w[8];
    f16x2 hv[8];
    #pragma unroll
    for (int u = 0; u < 8; ++u) {
      int idx = jj + u;
      bool ok = idx < degc;
      int s = ok ? cls[wid][idx] : cls[wid][0];
      w[u] = ok ? wls[wid][idx] : 0.f;
      hv[u] = *reinterpret_cast<const f16x2*>(&Hh[(size_t)s * D + lane * 2]);
    }
    #pragma unroll
    for (int u = 0; u < 8; ++u) {
      acc.x = fmaf(w[u], (float)hv[u][0], acc.x);
      acc.y = fmaf(w[u], (float)hv[u][1], acc.y);
    }
  }
  for (int jj = MAXDEG; jj < deg; ++jj) {   // cold fallback
    int s = col[start + jj];
    float e = alpha_s[s] + ad;
    e = e >= 0.f ? e : NEG_SLOPE * e;
    float w = expf(e - m);
    f16x2 hv = *reinterpret_cast<const f16x2*>(&Hh[(size_t)s * D + lane * 2]);
    acc.x = fmaf(w, (float)hv[0], acc.x);
    acc.y = fmaf(w, (float)hv[1], acc.y);
  }

  float2 bv = *reinterpret_cast<const float2*>(&bias[lane * 2]);
  float ox = fmaxf(acc.x * inv + bv.x, 0.f);
  float oy = fmaxf(acc.y * inv + bv.y, 0.f);
  if (FINAL) {
    float2 wv = *reinterpret_cast<const float2*>(&fcW[lane * 2]);
    float y = wave_sum(ox * wv.x + oy * wv.y);
    if (lane == 0) ynode[node] = y;
  } else {
    *reinterpret_cast<float2*>(&Out[(size_t)node * D + lane * 2]) = make_float2(ox, oy);
  }
}

// ---------------- finalize: per-graph mean of ynode + bias ----------------
__global__ __launch_bounds__(256) void k_final(const float* __restrict__ ynode,
                                               const int* __restrict__ batch,
                                               const float* __restrict__ fcb,
                                               float* __restrict__ out) {
  __shared__ float sm[256];
  int b = blockIdx.x;
  int tid = threadIdx.x;
  int lo = 0, hi = N_NODES;
  while (lo < hi) { int mid = (lo + hi) >> 1; if (batch[mid] < b) lo = mid + 1; else hi = mid; }
  int s0 = lo;
  lo = 0; hi = N_NODES;
  while (lo < hi) { int mid = (lo + hi) >> 1; if (batch[mid] < b + 1) lo = mid + 1; else hi = mid; }
  int s1 = lo;
  float sum = 0.f;
  for (int n = s0 + tid; n < s1; n += 256) sum += ynode[n];
  sm[tid] = sum;
  __syncthreads();
  #pragma unroll
  for (int off = 128; off > 0; off >>= 1) {
    if (tid < off) sm[tid] += sm[tid + off];
    __syncthreads();
  }
  if (tid == 0) out[b] = sm[0] / fmaxf((float)(s1 - s0), 1.f) + fcb[0];
}

extern "C" void kernel_launch(void* const* d_in, const int* in_sizes, int n_in,
                              void* d_out, int out_size, void* d_ws, size_t ws_size,
                              hipStream_t stream) {
  const float* x = (const float*)d_in[0];
  const int* ei = (const int*)d_in[1];
  const int* batch = (const int*)d_in[2];
  const float* W[4]   = {(const float*)d_in[3], (const float*)d_in[7],
                         (const float*)d_in[11], (const float*)d_in[15]};
  const float* asr[4] = {(const float*)d_in[4], (const float*)d_in[8],
                         (const float*)d_in[12], (const float*)d_in[16]};
  const float* adt[4] = {(const float*)d_in[5], (const float*)d_in[9],
                         (const float*)d_in[13], (const float*)d_in[17]};
  const float* bs[4]  = {(const float*)d_in[6], (const float*)d_in[10],
                         (const float*)d_in[14], (const float*)d_in[18]};
  const float* fcW = (const float*)d_in[19];
  const float* fcb = (const float*)d_in[20];
  float* out = (float*)d_out;

  char* ws = (char*)d_ws;
  size_t off = 0;
  float* hA = (float*)(ws + off); off += (size_t)N_NODES * D * 4;
  float* hB = (float*)(ws + off); off += (size_t)N_NODES * D * 4;
  _Float16* Hh = (_Float16*)(ws + off); off += (size_t)N_NODES * D * 2;
  float* alpha_s = (float*)(ws + off); off += (size_t)N_NODES * 4;
  float* alpha_d = (float*)(ws + off); off += (size_t)N_NODES * 4;
  int* cnt  = (int*)(ws + off); off += (size_t)N_NODES * 4;
  int* fill = (int*)(ws + off); off += (size_t)N_NODES * 4;
  int* rowptr = (int*)(ws + off); off += (size_t)(N_NODES + 1) * 4 + 12;
  int* col = (int*)(ws + off); off += (size_t)E_TOT * 4;
  float* ynode = (float*)(ws + off); off += (size_t)N_NODES * 4;
  int* partial = (int*)(ws + off); off += ((size_t)SCAN_GRID * 4 + 15) & ~15ull;
  _Float16* Whf[4];
  _Float16* Wlf[4];
  for (int lyr = 0; lyr < 4; ++lyr) {
    Whf[lyr] = (_Float16*)(ws + off); off += (size_t)D * D * 2;
    Wlf[lyr] = (_Float16*)(ws + off); off += (size_t)D * D * 2;
  }
  (void)ws_size; (void)in_sizes; (void)n_in; (void)out_size;

  hipMemsetAsync(cnt, 0, (size_t)N_NODES * 4 * 2, stream);  // zero cnt + fill
  WPtrs wp;
  for (int lyr = 0; lyr < 4; ++lyr) { wp.w[lyr] = W[lyr]; wp.h[lyr] = Whf[lyr]; wp.l[lyr] = Wlf[lyr]; }
  k_wconv_all<<<256, 256, 0, stream>>>(wp);
  int eb = (E_TOT + 255) / 256;
  k_count<<<eb, 256, 0, stream>>>(ei, cnt);
  k_scan1<<<SCAN_GRID, SCAN_BLK, 0, stream>>>(cnt, rowptr, partial);
  k_scan2<<<1, 64, 0, stream>>>(partial);
  k_scan3<<<SCAN_GRID, SCAN_BLK, 0, stream>>>(rowptr, partial);
  k_fill<<<eb, 256, 0, stream>>>(ei, rowptr, fill, col);

  const float* in = x;
  for (int l = 0; l < 4; ++l) {
    k_gemm_mfma<<<(N_NODES + 63) / 64, 256, 0, stream>>>(in, Whf[l], Wlf[l], hA, Hh,
                                                         asr[l], adt[l], alpha_s, alpha_d);
    if (l < 3) {
      k_agg<0><<<(N_NODES + 3) / 4, 256, 0, stream>>>(Hh, rowptr, col, alpha_s, alpha_d,
                                                      bs[l], hB, nullptr, nullptr);
    } else {
      k_agg<1><<<(N_NODES + 3) / 4, 256, 0, stream>>>(Hh, rowptr, col, alpha_s, alpha_d,
                                                      bs[l], nullptr, fcW, ynode);
    }
    in = hB;
  }
  k_final<<<N_GRAPHS, 256, 0, stream>>>(ynode, batch, fcb, out);
}

// Round 15
// 326.146 us; speedup vs baseline: 1.3087x; 1.0581x over previous
//
#include <hip/hip_runtime.h>

#define N_NODES 50000
#define N_EDGES 800000
#define E_TOT (N_EDGES + N_NODES)
#define D 128
#define N_GRAPHS 64
#define NEG_SLOPE 0.2f
#define MAXDEG 256
#define SCAN_BLK 1024
#define SCAN_GRID ((N_NODES + SCAN_BLK - 1) / SCAN_BLK)   // 49

typedef _Float16 f16x8 __attribute__((ext_vector_type(8)));
typedef _Float16 f16x2 __attribute__((ext_vector_type(2)));
typedef float f32x4 __attribute__((ext_vector_type(4)));

__device__ __forceinline__ float wave_max(float v) {
  #pragma unroll
  for (int off = 32; off > 0; off >>= 1) v = fmaxf(v, __shfl_xor(v, off));
  return v;
}
__device__ __forceinline__ float wave_sum(float v) {
  #pragma unroll
  for (int off = 32; off > 0; off >>= 1) v += __shfl_xor(v, off);
  return v;
}

// ---------------- CSR build ----------------
__global__ void k_count(const int* __restrict__ ei, int* __restrict__ cnt) {
  int e = blockIdx.x * blockDim.x + threadIdx.x;
  if (e >= E_TOT) return;
  int dst = (e < N_EDGES) ? ei[N_EDGES + e] : (e - N_EDGES);
  atomicAdd(&cnt[dst], 1);
}

__global__ __launch_bounds__(SCAN_BLK) void k_scan1(const int* __restrict__ cnt,
                                                    int* __restrict__ rowptr,
                                                    int* __restrict__ partial) {
  __shared__ int sm[SCAN_BLK];
  int i = blockIdx.x * SCAN_BLK + threadIdx.x;
  int v = (i < N_NODES) ? cnt[i] : 0;
  sm[threadIdx.x] = v;
  __syncthreads();
  #pragma unroll
  for (int off = 1; off < SCAN_BLK; off <<= 1) {
    int t = (threadIdx.x >= off) ? sm[threadIdx.x - off] : 0;
    __syncthreads();
    sm[threadIdx.x] += t;
    __syncthreads();
  }
  if (i < N_NODES) rowptr[i + 1] = sm[threadIdx.x];
  if (threadIdx.x == SCAN_BLK - 1) partial[blockIdx.x] = sm[threadIdx.x];
}

__global__ void k_scan2(int* __restrict__ partial) {
  int lane = threadIdx.x;
  int v = (lane < SCAN_GRID) ? partial[lane] : 0;
  #pragma unroll
  for (int off = 1; off < 64; off <<= 1) {
    int t = __shfl_up(v, off);
    if (lane >= off) v += t;
  }
  if (lane < SCAN_GRID) partial[lane] = v;
}

__global__ __launch_bounds__(SCAN_BLK) void k_scan3(int* __restrict__ rowptr,
                                                    const int* __restrict__ partial) {
  int i = blockIdx.x * SCAN_BLK + threadIdx.x;
  if (i == 0) rowptr[0] = 0;
  if (i < N_NODES && blockIdx.x > 0) rowptr[i + 1] += partial[blockIdx.x - 1];
}

// ---------------- all-layers W -> fp16 hi/lo fragment-order conversion ----------------
struct WPtrs {
  const float* w[4];
  _Float16* h[4];
  _Float16* l[4];
};
__global__ __launch_bounds__(256) void k_wconv_all(WPtrs p) {
  int layer = blockIdx.x >> 6;
  int e = (blockIdx.x & 63) * 256 + threadIdx.x;   // 0..16383
  int k = e >> 7, n = e & 127;
  float v = p.w[layer][e];
  _Float16 h = (_Float16)v;
  _Float16 lo = (_Float16)(v - (float)h);
  int idx = (n >> 4) * 2048 + (k >> 3) * 128 + (n & 15) * 8 + (k & 7);
  p.h[layer][idx] = h;
  p.l[layer][idx] = lo;
}

// ---------------- GEMM via fp16x2 split MFMA + alpha dots + fp16 H out (+ fused CSR fill) ----------------
template <int DO_FILL>
__global__ __launch_bounds__(256) void k_gemm_mfma(const float* __restrict__ X,
                                                   const _Float16* __restrict__ Whf,
                                                   const _Float16* __restrict__ Wlf,
                                                   _Float16* __restrict__ Hh,
                                                   const float* __restrict__ asrc,
                                                   const float* __restrict__ adst,
                                                   float* __restrict__ alpha_s,
                                                   float* __restrict__ alpha_d,
                                                   const int* __restrict__ ei,
                                                   const int* __restrict__ rowptr,
                                                   int* __restrict__ fill,
                                                   int* __restrict__ col) {
  __shared__ __align__(16) _Float16 AhL[8192];   // [w][kgf][r16][8]
  __shared__ __align__(16) _Float16 AlL[8192];
  const int tid = threadIdx.x;
  const int l = tid & 63;
  const int w = tid >> 6;
  const int rowbase = blockIdx.x * 64;

  #pragma unroll
  for (int p = 0; p < 4; ++p) {
    int row = p * 16 + (tid >> 4);
    int k0 = (tid & 15) * 8;
    int grow = rowbase + row;
    float xv[8];
    if (grow < N_NODES) {
      float4 f0 = *reinterpret_cast<const float4*>(&X[(size_t)grow * D + k0]);
      float4 f1 = *reinterpret_cast<const float4*>(&X[(size_t)grow * D + k0 + 4]);
      xv[0] = f0.x; xv[1] = f0.y; xv[2] = f0.z; xv[3] = f0.w;
      xv[4] = f1.x; xv[5] = f1.y; xv[6] = f1.z; xv[7] = f1.w;
    } else {
      #pragma unroll
      for (int j = 0; j < 8; ++j) xv[j] = 0.f;
    }
    f16x8 ah, al;
    #pragma unroll
    for (int j = 0; j < 8; ++j) {
      ah[j] = (_Float16)xv[j];
      al[j] = (_Float16)(xv[j] - (float)ah[j]);
    }
    int idx = (((row >> 4) * 16 + (k0 >> 3)) * 16 + (row & 15)) * 8;
    *reinterpret_cast<f16x8*>(&AhL[idx]) = ah;
    *reinterpret_cast<f16x8*>(&AlL[idx]) = al;
  }
  __syncthreads();

  f32x4 acc[8];
  #pragma unroll
  for (int cc = 0; cc < 8; ++cc) acc[cc] = (f32x4){0.f, 0.f, 0.f, 0.f};

  #pragma unroll
  for (int kt = 0; kt < 4; ++kt) {
    int aidx = w * 2048 + kt * 512 + l * 8;
    f16x8 ah = *reinterpret_cast<const f16x8*>(&AhL[aidx]);
    f16x8 al = *reinterpret_cast<const f16x8*>(&AlL[aidx]);
    #pragma unroll
    for (int cc = 0; cc < 8; ++cc) {
      int bidx = cc * 2048 + kt * 512 + l * 8;
      f16x8 bh = *reinterpret_cast<const f16x8*>(&Whf[bidx]);
      f16x8 bl = *reinterpret_cast<const f16x8*>(&Wlf[bidx]);
      acc[cc] = __builtin_amdgcn_mfma_f32_16x16x32_f16(ah, bh, acc[cc], 0, 0, 0);
      acc[cc] = __builtin_amdgcn_mfma_f32_16x16x32_f16(ah, bl, acc[cc], 0, 0, 0);
      acc[cc] = __builtin_amdgcn_mfma_f32_16x16x32_f16(al, bh, acc[cc], 0, 0, 0);
    }
  }

  const int myn = l & 15;
  const int rg4 = l >> 4;
  float asv[8], adv[8];
  #pragma unroll
  for (int cc = 0; cc < 8; ++cc) {
    asv[cc] = asrc[cc * 16 + myn];
    adv[cc] = adst[cc * 16 + myn];
  }
  #pragma unroll
  for (int reg = 0; reg < 4; ++reg) {
    int grow = rowbase + w * 16 + rg4 * 4 + reg;
    float ps = 0.f, pd = 0.f;
    #pragma unroll
    for (int cc = 0; cc < 8; ++cc) {
      float v = acc[cc][reg];
      ps = fmaf(v, asv[cc], ps);
      pd = fmaf(v, adv[cc], pd);
      if (grow < N_NODES) Hh[(size_t)grow * D + cc * 16 + myn] = (_Float16)v;
    }
    #pragma unroll
    for (int off = 1; off < 16; off <<= 1) {
      ps += __shfl_xor(ps, off);
      pd += __shfl_xor(pd, off);
    }
    if (grow < N_NODES && myn == 0) {
      alpha_s[grow] = ps;
      alpha_d[grow] = pd;
    }
  }

  // fused CSR fill (layer 1 only): scatter latency hides under other waves' MFMA
  if (DO_FILL) {
    int stride = gridDim.x * blockDim.x;
    for (int e = blockIdx.x * blockDim.x + tid; e < E_TOT; e += stride) {
      int src, dst;
      if (e < N_EDGES) { src = ei[e]; dst = ei[N_EDGES + e]; }
      else { src = e - N_EDGES; dst = src; }
      int pos = rowptr[dst] + atomicAdd(&fill[dst], 1);
      col[pos] = src;
    }
  }
}

// ---------------- fused segment softmax + aggregate (fp16 gather) + bias + relu ----------------
template <int FINAL>
__global__ __launch_bounds__(256) void k_agg(const _Float16* __restrict__ Hh,
                                             const int* __restrict__ rowptr,
                                             const int* __restrict__ col,
                                             const float* __restrict__ alpha_s,
                                             const float* __restrict__ alpha_d,
                                             const float* __restrict__ bias,
                                             float* __restrict__ Out,
                                             const float* __restrict__ fcW,
                                             float* __restrict__ ynode) {
  __shared__ float wls[4][MAXDEG];
  __shared__ int cls[4][MAXDEG];
  int wid = threadIdx.x >> 6;
  int lane = threadIdx.x & 63;
  int node = blockIdx.x * 4 + wid;
  if (node >= N_NODES) return;
  int start = rowptr[node], end = rowptr[node + 1];
  int deg = end - start;
  float ad = alpha_d[node];

  // pass 1: e into registers + cols into LDS, wave max
  float earr[4];
  float m = -1e30f;
  #pragma unroll
  for (int k = 0; k < 4; ++k) {
    int j0 = lane + k * 64;
    earr[k] = -1e30f;
    if (j0 < deg) {
      int s = col[start + j0];
      float e = alpha_s[s] + ad;
      e = e >= 0.f ? e : NEG_SLOPE * e;
      cls[wid][j0] = s;
      earr[k] = e;
    }
  }
  m = fmaxf(fmaxf(earr[0], earr[1]), fmaxf(earr[2], earr[3]));
  for (int j0 = MAXDEG + lane; j0 < deg; j0 += 64) {
    int s = col[start + j0];
    float e = alpha_s[s] + ad;
    e = e >= 0.f ? e : NEG_SLOPE * e;
    m = fmaxf(m, e);
  }
  m = wave_max(m);

  // pass 2: weights into LDS, wave sum
  float dsum = 0.f;
  #pragma unroll
  for (int k = 0; k < 4; ++k) {
    int j0 = lane + k * 64;
    if (j0 < deg) {
      float w = expf(earr[k] - m);
      wls[wid][j0] = w;
      dsum += w;
    }
  }
  for (int j0 = MAXDEG + lane; j0 < deg; j0 += 64) {
    int s = col[start + j0];
    float e = alpha_s[s] + ad;
    e = e >= 0.f ? e : NEG_SLOPE * e;
    dsum += expf(e - m);
  }
  dsum = wave_sum(dsum);
  float inv = 1.f / (dsum + 1e-16f);

  // pass 3: fp16 gather in masked batches of 8 (8 loads in flight)
  float2 acc = make_float2(0.f, 0.f);
  int degc = deg < MAXDEG ? deg : MAXDEG;
  for (int jj = 0; jj < degc; jj += 8) {
    float w[8];
    f16x2 hv[8];
    #pragma unroll
    for (int u = 0; u < 8; ++u) {
      int idx = jj + u;
      bool ok = idx < degc;
      int s = ok ? cls[wid][idx] : cls[wid][0];
      w[u] = ok ? wls[wid][idx] : 0.f;
      hv[u] = *reinterpret_cast<const f16x2*>(&Hh[(size_t)s * D + lane * 2]);
    }
    #pragma unroll
    for (int u = 0; u < 8; ++u) {
      acc.x = fmaf(w[u], (float)hv[u][0], acc.x);
      acc.y = fmaf(w[u], (float)hv[u][1], acc.y);
    }
  }
  for (int jj = MAXDEG; jj < deg; ++jj) {   // cold fallback
    int s = col[start + jj];
    float e = alpha_s[s] + ad;
    e = e >= 0.f ? e : NEG_SLOPE * e;
    float w = expf(e - m);
    f16x2 hv = *reinterpret_cast<const f16x2*>(&Hh[(size_t)s * D + lane * 2]);
    acc.x = fmaf(w, (float)hv[0], acc.x);
    acc.y = fmaf(w, (float)hv[1], acc.y);
  }

  float2 bv = *reinterpret_cast<const float2*>(&bias[lane * 2]);
  float ox = fmaxf(acc.x * inv + bv.x, 0.f);
  float oy = fmaxf(acc.y * inv + bv.y, 0.f);
  if (FINAL) {
    float2 wv = *reinterpret_cast<const float2*>(&fcW[lane * 2]);
    float y = wave_sum(ox * wv.x + oy * wv.y);
    if (lane == 0) ynode[node] = y;
  } else {
    *reinterpret_cast<float2*>(&Out[(size_t)node * D + lane * 2]) = make_float2(ox, oy);
  }
}

// ---------------- finalize: per-graph mean of ynode + bias ----------------
__global__ __launch_bounds__(256) void k_final(const float* __restrict__ ynode,
                                               const int* __restrict__ batch,
                                               const float* __restrict__ fcb,
                                               float* __restrict__ out) {
  __shared__ float sm[256];
  int b = blockIdx.x;
  int tid = threadIdx.x;
  int lo = 0, hi = N_NODES;
  while (lo < hi) { int mid = (lo + hi) >> 1; if (batch[mid] < b) lo = mid + 1; else hi = mid; }
  int s0 = lo;
  lo = 0; hi = N_NODES;
  while (lo < hi) { int mid = (lo + hi) >> 1; if (batch[mid] < b + 1) lo = mid + 1; else hi = mid; }
  int s1 = lo;
  float sum = 0.f;
  for (int n = s0 + tid; n < s1; n += 256) sum += ynode[n];
  sm[tid] = sum;
  __syncthreads();
  #pragma unroll
  for (int off = 128; off > 0; off >>= 1) {
    if (tid < off) sm[tid] += sm[tid + off];
    __syncthreads();
  }
  if (tid == 0) out[b] = sm[0] / fmaxf((float)(s1 - s0), 1.f) + fcb[0];
}

extern "C" void kernel_launch(void* const* d_in, const int* in_sizes, int n_in,
                              void* d_out, int out_size, void* d_ws, size_t ws_size,
                              hipStream_t stream) {
  const float* x = (const float*)d_in[0];
  const int* ei = (const int*)d_in[1];
  const int* batch = (const int*)d_in[2];
  const float* W[4]   = {(const float*)d_in[3], (const float*)d_in[7],
                         (const float*)d_in[11], (const float*)d_in[15]};
  const float* asr[4] = {(const float*)d_in[4], (const float*)d_in[8],
                         (const float*)d_in[12], (const float*)d_in[16]};
  const float* adt[4] = {(const float*)d_in[5], (const float*)d_in[9],
                         (const float*)d_in[13], (const float*)d_in[17]};
  const float* bs[4]  = {(const float*)d_in[6], (const float*)d_in[10],
                         (const float*)d_in[14], (const float*)d_in[18]};
  const float* fcW = (const float*)d_in[19];
  const float* fcb = (const float*)d_in[20];
  float* out = (float*)d_out;

  char* ws = (char*)d_ws;
  size_t off = 0;
  float* hB = (float*)(ws + off); off += (size_t)N_NODES * D * 4;
  _Float16* Hh = (_Float16*)(ws + off); off += (size_t)N_NODES * D * 2;
  float* alpha_s = (float*)(ws + off); off += (size_t)N_NODES * 4;
  float* alpha_d = (float*)(ws + off); off += (size_t)N_NODES * 4;
  int* cnt  = (int*)(ws + off); off += (size_t)N_NODES * 4;
  int* fill = (int*)(ws + off); off += (size_t)N_NODES * 4;   // contiguous after cnt
  int* rowptr = (int*)(ws + off); off += (size_t)(N_NODES + 1) * 4 + 12;
  int* col = (int*)(ws + off); off += (size_t)E_TOT * 4;
  float* ynode = (float*)(ws + off); off += (size_t)N_NODES * 4;
  int* partial = (int*)(ws + off); off += ((size_t)SCAN_GRID * 4 + 15) & ~15ull;
  _Float16* Whf[4];
  _Float16* Wlf[4];
  for (int lyr = 0; lyr < 4; ++lyr) {
    Whf[lyr] = (_Float16*)(ws + off); off += (size_t)D * D * 2;
    Wlf[lyr] = (_Float16*)(ws + off); off += (size_t)D * D * 2;
  }
  (void)ws_size; (void)in_sizes; (void)n_in; (void)out_size;

  hipMemsetAsync(cnt, 0, (size_t)N_NODES * 4 * 2, stream);  // zero cnt + fill
  WPtrs wp;
  for (int lyr = 0; lyr < 4; ++lyr) { wp.w[lyr] = W[lyr]; wp.h[lyr] = Whf[lyr]; wp.l[lyr] = Wlf[lyr]; }
  k_wconv_all<<<256, 256, 0, stream>>>(wp);
  int eb = (E_TOT + 255) / 256;
  k_count<<<eb, 256, 0, stream>>>(ei, cnt);
  k_scan1<<<SCAN_GRID, SCAN_BLK, 0, stream>>>(cnt, rowptr, partial);
  k_scan2<<<1, 64, 0, stream>>>(partial);
  k_scan3<<<SCAN_GRID, SCAN_BLK, 0, stream>>>(rowptr, partial);

  int gb = (N_NODES + 63) / 64;
  // layer 1: gemm + fused CSR fill
  k_gemm_mfma<1><<<gb, 256, 0, stream>>>(x, Whf[0], Wlf[0], Hh, asr[0], adt[0],
                                         alpha_s, alpha_d, ei, rowptr, fill, col);
  k_agg<0><<<(N_NODES + 3) / 4, 256, 0, stream>>>(Hh, rowptr, col, alpha_s, alpha_d,
                                                  bs[0], hB, nullptr, nullptr);
  for (int l = 1; l < 4; ++l) {
    k_gemm_mfma<0><<<gb, 256, 0, stream>>>(hB, Whf[l], Wlf[l], Hh, asr[l], adt[l],
                                           alpha_s, alpha_d, nullptr, nullptr,
                                           nullptr, nullptr);
    if (l < 3) {
      k_agg<0><<<(N_NODES + 3) / 4, 256, 0, stream>>>(Hh, rowptr, col, alpha_s, alpha_d,
                                                      bs[l], hB, nullptr, nullptr);
    } else {
      k_agg<1><<<(N_NODES + 3) / 4, 256, 0, stream>>>(Hh, rowptr, col, alpha_s, alpha_d,
                                                      bs[l], nullptr, fcW, ynode);
    }
  }
  k_final<<<N_GRAPHS, 256, 0, stream>>>(ynode, batch, fcb, out);
}

// Round 16
// 297.294 us; speedup vs baseline: 1.4357x; 1.0970x over previous
//
#include <hip/hip_runtime.h>

#define N_NODES 50000
#define N_EDGES 800000
#define E_TOT (N_EDGES + N_NODES)
#define D 128
#define N_GRAPHS 64
#define NEG_SLOPE 0.2f
#define MAXDEG 256
#define SCAN_BLK 1024
#define SCAN_GRID ((N_NODES + SCAN_BLK - 1) / SCAN_BLK)   // 49

typedef _Float16 f16x8 __attribute__((ext_vector_type(8)));
typedef _Float16 f16x2 __attribute__((ext_vector_type(2)));
typedef float f32x4 __attribute__((ext_vector_type(4)));

__device__ __forceinline__ float wave_max(float v) {
  #pragma unroll
  for (int off = 32; off > 0; off >>= 1) v = fmaxf(v, __shfl_xor(v, off));
  return v;
}
__device__ __forceinline__ float wave_sum(float v) {
  #pragma unroll
  for (int off = 32; off > 0; off >>= 1) v += __shfl_xor(v, off);
  return v;
}

// ---------------- CSR build: count + per-edge rank ----------------
__global__ void k_count(const int* __restrict__ ei, int* __restrict__ cnt,
                        unsigned short* __restrict__ rank) {
  int e = blockIdx.x * blockDim.x + threadIdx.x;
  if (e >= E_TOT) return;
  int dst = (e < N_EDGES) ? ei[N_EDGES + e] : (e - N_EDGES);
  rank[e] = (unsigned short)atomicAdd(&cnt[dst], 1);
}

__global__ __launch_bounds__(SCAN_BLK) void k_scan1(const int* __restrict__ cnt,
                                                    int* __restrict__ rowptr,
                                                    int* __restrict__ partial) {
  __shared__ int sm[SCAN_BLK];
  int i = blockIdx.x * SCAN_BLK + threadIdx.x;
  int v = (i < N_NODES) ? cnt[i] : 0;
  sm[threadIdx.x] = v;
  __syncthreads();
  #pragma unroll
  for (int off = 1; off < SCAN_BLK; off <<= 1) {
    int t = (threadIdx.x >= off) ? sm[threadIdx.x - off] : 0;
    __syncthreads();
    sm[threadIdx.x] += t;
    __syncthreads();
  }
  if (i < N_NODES) rowptr[i + 1] = sm[threadIdx.x];
  if (threadIdx.x == SCAN_BLK - 1) partial[blockIdx.x] = sm[threadIdx.x];
}

__global__ void k_scan2(int* __restrict__ partial) {
  int lane = threadIdx.x;
  int v = (lane < SCAN_GRID) ? partial[lane] : 0;
  #pragma unroll
  for (int off = 1; off < 64; off <<= 1) {
    int t = __shfl_up(v, off);
    if (lane >= off) v += t;
  }
  if (lane < SCAN_GRID) partial[lane] = v;
}

__global__ __launch_bounds__(SCAN_BLK) void k_scan3(int* __restrict__ rowptr,
                                                    const int* __restrict__ partial) {
  int i = blockIdx.x * SCAN_BLK + threadIdx.x;
  if (i == 0) rowptr[0] = 0;
  if (i < N_NODES && blockIdx.x > 0) rowptr[i + 1] += partial[blockIdx.x - 1];
}

// ---------------- all-layers W -> fp16 hi/lo fragment-order conversion ----------------
struct WPtrs {
  const float* w[4];
  _Float16* h[4];
  _Float16* l[4];
};
__global__ __launch_bounds__(256) void k_wconv_all(WPtrs p) {
  int layer = blockIdx.x >> 6;
  int e = (blockIdx.x & 63) * 256 + threadIdx.x;   // 0..16383
  int k = e >> 7, n = e & 127;
  float v = p.w[layer][e];
  _Float16 h = (_Float16)v;
  _Float16 lo = (_Float16)(v - (float)h);
  int idx = (n >> 4) * 2048 + (k >> 3) * 128 + (n & 15) * 8 + (k & 7);
  p.h[layer][idx] = h;
  p.l[layer][idx] = lo;
}

// ---------------- GEMM via MFMA + alpha dots + fp16 H out ----------------
// MODE 1: fp32 input, full hi/lo split (3 MFMA), + fused atomic-free CSR fill (layer 1)
// MODE 0: fp16 input (exact), 2 MFMA, half LDS (layers 2-4)
template <int MODE>
__global__ __launch_bounds__(256) void k_gemm_mfma(const void* __restrict__ Xv,
                                                   const _Float16* __restrict__ Whf,
                                                   const _Float16* __restrict__ Wlf,
                                                   _Float16* __restrict__ Hh,
                                                   const float* __restrict__ asrc,
                                                   const float* __restrict__ adst,
                                                   float* __restrict__ alpha_s,
                                                   float* __restrict__ alpha_d,
                                                   const int* __restrict__ ei,
                                                   const int* __restrict__ rowptr,
                                                   const unsigned short* __restrict__ rank,
                                                   unsigned short* __restrict__ col) {
  __shared__ __align__(16) _Float16 AhL[8192];   // [w][kgf][r16][8]
  __shared__ __align__(16) _Float16 AlL[MODE ? 8192 : 1];
  const int tid = threadIdx.x;
  const int l = tid & 63;
  const int w = tid >> 6;
  const int rowbase = blockIdx.x * 64;

  #pragma unroll
  for (int p = 0; p < 4; ++p) {
    int row = p * 16 + (tid >> 4);
    int k0 = (tid & 15) * 8;
    int grow = rowbase + row;
    int idx = (((row >> 4) * 16 + (k0 >> 3)) * 16 + (row & 15)) * 8;
    if (MODE) {
      const float* X = (const float*)Xv;
      float xv[8];
      if (grow < N_NODES) {
        float4 f0 = *reinterpret_cast<const float4*>(&X[(size_t)grow * D + k0]);
        float4 f1 = *reinterpret_cast<const float4*>(&X[(size_t)grow * D + k0 + 4]);
        xv[0] = f0.x; xv[1] = f0.y; xv[2] = f0.z; xv[3] = f0.w;
        xv[4] = f1.x; xv[5] = f1.y; xv[6] = f1.z; xv[7] = f1.w;
      } else {
        #pragma unroll
        for (int j = 0; j < 8; ++j) xv[j] = 0.f;
      }
      f16x8 ah, al;
      #pragma unroll
      for (int j = 0; j < 8; ++j) {
        ah[j] = (_Float16)xv[j];
        al[j] = (_Float16)(xv[j] - (float)ah[j]);
      }
      *reinterpret_cast<f16x8*>(&AhL[idx]) = ah;
      *reinterpret_cast<f16x8*>(&AlL[idx]) = al;
    } else {
      const _Float16* X = (const _Float16*)Xv;
      f16x8 ah = {0, 0, 0, 0, 0, 0, 0, 0};
      if (grow < N_NODES)
        ah = *reinterpret_cast<const f16x8*>(&X[(size_t)grow * D + k0]);
      *reinterpret_cast<f16x8*>(&AhL[idx]) = ah;
    }
  }
  __syncthreads();

  f32x4 acc[8];
  #pragma unroll
  for (int cc = 0; cc < 8; ++cc) acc[cc] = (f32x4){0.f, 0.f, 0.f, 0.f};

  #pragma unroll
  for (int kt = 0; kt < 4; ++kt) {
    int aidx = w * 2048 + kt * 512 + l * 8;
    f16x8 ah = *reinterpret_cast<const f16x8*>(&AhL[aidx]);
    f16x8 al;
    if (MODE) al = *reinterpret_cast<const f16x8*>(&AlL[aidx]);
    #pragma unroll
    for (int cc = 0; cc < 8; ++cc) {
      int bidx = cc * 2048 + kt * 512 + l * 8;
      f16x8 bh = *reinterpret_cast<const f16x8*>(&Whf[bidx]);
      f16x8 bl = *reinterpret_cast<const f16x8*>(&Wlf[bidx]);
      acc[cc] = __builtin_amdgcn_mfma_f32_16x16x32_f16(ah, bh, acc[cc], 0, 0, 0);
      acc[cc] = __builtin_amdgcn_mfma_f32_16x16x32_f16(ah, bl, acc[cc], 0, 0, 0);
      if (MODE)
        acc[cc] = __builtin_amdgcn_mfma_f32_16x16x32_f16(al, bh, acc[cc], 0, 0, 0);
    }
  }

  const int myn = l & 15;
  const int rg4 = l >> 4;
  float asv[8], adv[8];
  #pragma unroll
  for (int cc = 0; cc < 8; ++cc) {
    asv[cc] = asrc[cc * 16 + myn];
    adv[cc] = adst[cc * 16 + myn];
  }
  #pragma unroll
  for (int reg = 0; reg < 4; ++reg) {
    int grow = rowbase + w * 16 + rg4 * 4 + reg;
    float ps = 0.f, pd = 0.f;
    #pragma unroll
    for (int cc = 0; cc < 8; ++cc) {
      float v = acc[cc][reg];
      ps = fmaf(v, asv[cc], ps);
      pd = fmaf(v, adv[cc], pd);
      if (grow < N_NODES) Hh[(size_t)grow * D + cc * 16 + myn] = (_Float16)v;
    }
    #pragma unroll
    for (int off = 1; off < 16; off <<= 1) {
      ps += __shfl_xor(ps, off);
      pd += __shfl_xor(pd, off);
    }
    if (grow < N_NODES && myn == 0) {
      alpha_s[grow] = ps;
      alpha_d[grow] = pd;
    }
  }

  // fused atomic-free CSR fill (layer 1): rank precomputed by k_count
  if (MODE) {
    int stride = gridDim.x * blockDim.x;
    for (int e = blockIdx.x * blockDim.x + tid; e < E_TOT; e += stride) {
      int src, dst;
      if (e < N_EDGES) { src = ei[e]; dst = ei[N_EDGES + e]; }
      else { src = e - N_EDGES; dst = src; }
      col[rowptr[dst] + rank[e]] = (unsigned short)src;
    }
  }
}

// ---------------- fused segment softmax + aggregate (fp16 gather) + bias + relu ----------------
template <int FINAL>
__global__ __launch_bounds__(256) void k_agg(const _Float16* __restrict__ Hh,
                                             const int* __restrict__ rowptr,
                                             const unsigned short* __restrict__ col,
                                             const float* __restrict__ alpha_s,
                                             const float* __restrict__ alpha_d,
                                             const float* __restrict__ bias,
                                             _Float16* __restrict__ Out,
                                             const float* __restrict__ fcW,
                                             float* __restrict__ ynode) {
  __shared__ float wls[4][MAXDEG];
  __shared__ int cls[4][MAXDEG];
  int wid = threadIdx.x >> 6;
  int lane = threadIdx.x & 63;
  int node = blockIdx.x * 4 + wid;
  if (node >= N_NODES) return;
  int start = rowptr[node], end = rowptr[node + 1];
  int deg = end - start;
  float ad = alpha_d[node];

  // pass 1: e into registers + cols into LDS, wave max
  float earr[4];
  float m = -1e30f;
  #pragma unroll
  for (int k = 0; k < 4; ++k) {
    int j0 = lane + k * 64;
    earr[k] = -1e30f;
    if (j0 < deg) {
      int s = col[start + j0];
      float e = alpha_s[s] + ad;
      e = e >= 0.f ? e : NEG_SLOPE * e;
      cls[wid][j0] = s;
      earr[k] = e;
    }
  }
  m = fmaxf(fmaxf(earr[0], earr[1]), fmaxf(earr[2], earr[3]));
  for (int j0 = MAXDEG + lane; j0 < deg; j0 += 64) {
    int s = col[start + j0];
    float e = alpha_s[s] + ad;
    e = e >= 0.f ? e : NEG_SLOPE * e;
    m = fmaxf(m, e);
  }
  m = wave_max(m);

  // pass 2: weights into LDS, wave sum
  float dsum = 0.f;
  #pragma unroll
  for (int k = 0; k < 4; ++k) {
    int j0 = lane + k * 64;
    if (j0 < deg) {
      float w = expf(earr[k] - m);
      wls[wid][j0] = w;
      dsum += w;
    }
  }
  for (int j0 = MAXDEG + lane; j0 < deg; j0 += 64) {
    int s = col[start + j0];
    float e = alpha_s[s] + ad;
    e = e >= 0.f ? e : NEG_SLOPE * e;
    dsum += expf(e - m);
  }
  dsum = wave_sum(dsum);
  float inv = 1.f / (dsum + 1e-16f);

  // pass 3: fp16 gather in masked batches of 8 (8 loads in flight)
  float2 acc = make_float2(0.f, 0.f);
  int degc = deg < MAXDEG ? deg : MAXDEG;
  for (int jj = 0; jj < degc; jj += 8) {
    float w[8];
    f16x2 hv[8];
    #pragma unroll
    for (int u = 0; u < 8; ++u) {
      int idx = jj + u;
      bool ok = idx < degc;
      int s = ok ? cls[wid][idx] : cls[wid][0];
      w[u] = ok ? wls[wid][idx] : 0.f;
      hv[u] = *reinterpret_cast<const f16x2*>(&Hh[(size_t)s * D + lane * 2]);
    }
    #pragma unroll
    for (int u = 0; u < 8; ++u) {
      acc.x = fmaf(w[u], (float)hv[u][0], acc.x);
      acc.y = fmaf(w[u], (float)hv[u][1], acc.y);
    }
  }
  for (int jj = MAXDEG; jj < deg; ++jj) {   // cold fallback
    int s = col[start + jj];
    float e = alpha_s[s] + ad;
    e = e >= 0.f ? e : NEG_SLOPE * e;
    float w = expf(e - m);
    f16x2 hv = *reinterpret_cast<const f16x2*>(&Hh[(size_t)s * D + lane * 2]);
    acc.x = fmaf(w, (float)hv[0], acc.x);
    acc.y = fmaf(w, (float)hv[1], acc.y);
  }

  float2 bv = *reinterpret_cast<const float2*>(&bias[lane * 2]);
  float ox = fmaxf(acc.x * inv + bv.x, 0.f);
  float oy = fmaxf(acc.y * inv + bv.y, 0.f);
  if (FINAL) {
    float2 wv = *reinterpret_cast<const float2*>(&fcW[lane * 2]);
    float y = wave_sum(ox * wv.x + oy * wv.y);
    if (lane == 0) ynode[node] = y;
  } else {
    f16x2 o;
    o[0] = (_Float16)ox;
    o[1] = (_Float16)oy;
    *reinterpret_cast<f16x2*>(&Out[(size_t)node * D + lane * 2]) = o;
  }
}

// ---------------- finalize: per-graph mean of ynode + bias ----------------
__global__ __launch_bounds__(256) void k_final(const float* __restrict__ ynode,
                                               const int* __restrict__ batch,
                                               const float* __restrict__ fcb,
                                               float* __restrict__ out) {
  __shared__ float sm[256];
  int b = blockIdx.x;
  int tid = threadIdx.x;
  int lo = 0, hi = N_NODES;
  while (lo < hi) { int mid = (lo + hi) >> 1; if (batch[mid] < b) lo = mid + 1; else hi = mid; }
  int s0 = lo;
  lo = 0; hi = N_NODES;
  while (lo < hi) { int mid = (lo + hi) >> 1; if (batch[mid] < b + 1) lo = mid + 1; else hi = mid; }
  int s1 = lo;
  float sum = 0.f;
  for (int n = s0 + tid; n < s1; n += 256) sum += ynode[n];
  sm[tid] = sum;
  __syncthreads();
  #pragma unroll
  for (int off = 128; off > 0; off >>= 1) {
    if (tid < off) sm[tid] += sm[tid + off];
    __syncthreads();
  }
  if (tid == 0) out[b] = sm[0] / fmaxf((float)(s1 - s0), 1.f) + fcb[0];
}

extern "C" void kernel_launch(void* const* d_in, const int* in_sizes, int n_in,
                              void* d_out, int out_size, void* d_ws, size_t ws_size,
                              hipStream_t stream) {
  const float* x = (const float*)d_in[0];
  const int* ei = (const int*)d_in[1];
  const int* batch = (const int*)d_in[2];
  const float* W[4]   = {(const float*)d_in[3], (const float*)d_in[7],
                         (const float*)d_in[11], (const float*)d_in[15]};
  const float* asr[4] = {(const float*)d_in[4], (const float*)d_in[8],
                         (const float*)d_in[12], (const float*)d_in[16]};
  const float* adt[4] = {(const float*)d_in[5], (const float*)d_in[9],
                         (const float*)d_in[13], (const float*)d_in[17]};
  const float* bs[4]  = {(const float*)d_in[6], (const float*)d_in[10],
                         (const float*)d_in[14], (const float*)d_in[18]};
  const float* fcW = (const float*)d_in[19];
  const float* fcb = (const float*)d_in[20];
  float* out = (float*)d_out;

  char* ws = (char*)d_ws;
  size_t off = 0;
  _Float16* Hh  = (_Float16*)(ws + off); off += (size_t)N_NODES * D * 2;
  _Float16* hBh = (_Float16*)(ws + off); off += (size_t)N_NODES * D * 2;
  float* alpha_s = (float*)(ws + off); off += (size_t)N_NODES * 4;
  float* alpha_d = (float*)(ws + off); off += (size_t)N_NODES * 4;
  int* cnt  = (int*)(ws + off); off += (size_t)N_NODES * 4;
  int* rowptr = (int*)(ws + off); off += (size_t)(N_NODES + 1) * 4 + 12;
  unsigned short* col = (unsigned short*)(ws + off); off += ((size_t)E_TOT * 2 + 15) & ~15ull;
  unsigned short* rank = (unsigned short*)(ws + off); off += ((size_t)E_TOT * 2 + 15) & ~15ull;
  float* ynode = (float*)(ws + off); off += (size_t)N_NODES * 4;
  int* partial = (int*)(ws + off); off += ((size_t)SCAN_GRID * 4 + 15) & ~15ull;
  _Float16* Whf[4];
  _Float16* Wlf[4];
  for (int lyr = 0; lyr < 4; ++lyr) {
    Whf[lyr] = (_Float16*)(ws + off); off += (size_t)D * D * 2;
    Wlf[lyr] = (_Float16*)(ws + off); off += (size_t)D * D * 2;
  }
  (void)ws_size; (void)in_sizes; (void)n_in; (void)out_size;

  hipMemsetAsync(cnt, 0, (size_t)N_NODES * 4, stream);
  WPtrs wp;
  for (int lyr = 0; lyr < 4; ++lyr) { wp.w[lyr] = W[lyr]; wp.h[lyr] = Whf[lyr]; wp.l[lyr] = Wlf[lyr]; }
  k_wconv_all<<<256, 256, 0, stream>>>(wp);
  int eb = (E_TOT + 255) / 256;
  k_count<<<eb, 256, 0, stream>>>(ei, cnt, rank);
  k_scan1<<<SCAN_GRID, SCAN_BLK, 0, stream>>>(cnt, rowptr, partial);
  k_scan2<<<1, 64, 0, stream>>>(partial);
  k_scan3<<<SCAN_GRID, SCAN_BLK, 0, stream>>>(rowptr, partial);

  int gb = (N_NODES + 63) / 64;
  // layer 1: gemm (fp32 input, full split) + fused atomic-free CSR fill
  k_gemm_mfma<1><<<gb, 256, 0, stream>>>(x, Whf[0], Wlf[0], Hh, asr[0], adt[0],
                                         alpha_s, alpha_d, ei, rowptr, rank, col);
  k_agg<0><<<(N_NODES + 3) / 4, 256, 0, stream>>>(Hh, rowptr, col, alpha_s, alpha_d,
                                                  bs[0], hBh, nullptr, nullptr);
  for (int l = 1; l < 4; ++l) {
    k_gemm_mfma<0><<<gb, 256, 0, stream>>>(hBh, Whf[l], Wlf[l], Hh, asr[l], adt[l],
                                           alpha_s, alpha_d, nullptr, nullptr,
                                           nullptr, nullptr);
    if (l < 3) {
      k_agg<0><<<(N_NODES + 3) / 4, 256, 0, stream>>>(Hh, rowptr, col, alpha_s, alpha_d,
                                                      bs[l], hBh, nullptr, nullptr);
    } else {
      k_agg<1><<<(N_NODES + 3) / 4, 256, 0, stream>>>(Hh, rowptr, col, alpha_s, alpha_d,
                                                      bs[l], nullptr, fcW, ynode);
    }
  }
  k_final<<<N_GRAPHS, 256, 0, stream>>>(ynode, batch, fcb, out);
}

// Round 17
// 291.121 us; speedup vs baseline: 1.4662x; 1.0212x over previous
//
#include <hip/hip_runtime.h>

#define N_NODES 50000
#define N_EDGES 800000
#define E_TOT (N_EDGES + N_NODES)
#define D 128
#define N_GRAPHS 64
#define NEG_SLOPE 0.2f
#define MAXDEG 256
#define SCAN_BLK 1024
#define SCAN_GRID ((N_NODES + SCAN_BLK - 1) / SCAN_BLK)   // 49

typedef _Float16 f16x8 __attribute__((ext_vector_type(8)));
typedef _Float16 f16x4 __attribute__((ext_vector_type(4)));
typedef _Float16 f16x2 __attribute__((ext_vector_type(2)));
typedef float f32x4 __attribute__((ext_vector_type(4)));

__device__ __forceinline__ float wave_max(float v) {
  #pragma unroll
  for (int off = 32; off > 0; off >>= 1) v = fmaxf(v, __shfl_xor(v, off));
  return v;
}
__device__ __forceinline__ float wave_sum(float v) {
  #pragma unroll
  for (int off = 32; off > 0; off >>= 1) v += __shfl_xor(v, off);
  return v;
}

// ---------------- CSR build: count + per-edge rank ----------------
__global__ void k_count(const int* __restrict__ ei, int* __restrict__ cnt,
                        unsigned short* __restrict__ rank) {
  int e = blockIdx.x * blockDim.x + threadIdx.x;
  if (e >= E_TOT) return;
  int dst = (e < N_EDGES) ? ei[N_EDGES + e] : (e - N_EDGES);
  rank[e] = (unsigned short)atomicAdd(&cnt[dst], 1);
}

__global__ __launch_bounds__(SCAN_BLK) void k_scan1(const int* __restrict__ cnt,
                                                    int* __restrict__ rowptr,
                                                    int* __restrict__ partial) {
  __shared__ int sm[SCAN_BLK];
  int i = blockIdx.x * SCAN_BLK + threadIdx.x;
  int v = (i < N_NODES) ? cnt[i] : 0;
  sm[threadIdx.x] = v;
  __syncthreads();
  #pragma unroll
  for (int off = 1; off < SCAN_BLK; off <<= 1) {
    int t = (threadIdx.x >= off) ? sm[threadIdx.x - off] : 0;
    __syncthreads();
    sm[threadIdx.x] += t;
    __syncthreads();
  }
  if (i < N_NODES) rowptr[i + 1] = sm[threadIdx.x];
  if (threadIdx.x == SCAN_BLK - 1) partial[blockIdx.x] = sm[threadIdx.x];
}

__global__ void k_scan2(int* __restrict__ partial) {
  int lane = threadIdx.x;
  int v = (lane < SCAN_GRID) ? partial[lane] : 0;
  #pragma unroll
  for (int off = 1; off < 64; off <<= 1) {
    int t = __shfl_up(v, off);
    if (lane >= off) v += t;
  }
  if (lane < SCAN_GRID) partial[lane] = v;
}

__global__ __launch_bounds__(SCAN_BLK) void k_scan3(int* __restrict__ rowptr,
                                                    const int* __restrict__ partial) {
  int i = blockIdx.x * SCAN_BLK + threadIdx.x;
  if (i == 0) rowptr[0] = 0;
  if (i < N_NODES && blockIdx.x > 0) rowptr[i + 1] += partial[blockIdx.x - 1];
}

// ---------------- all-layers W -> fp16 hi/lo fragment-order conversion ----------------
struct WPtrs {
  const float* w[4];
  _Float16* h[4];
  _Float16* l[4];
};
__global__ __launch_bounds__(256) void k_wconv_all(WPtrs p) {
  int layer = blockIdx.x >> 6;
  int e = (blockIdx.x & 63) * 256 + threadIdx.x;   // 0..16383
  int k = e >> 7, n = e & 127;
  float v = p.w[layer][e];
  _Float16 h = (_Float16)v;
  _Float16 lo = (_Float16)(v - (float)h);
  int idx = (n >> 4) * 2048 + (k >> 3) * 128 + (n & 15) * 8 + (k & 7);
  p.h[layer][idx] = h;
  p.l[layer][idx] = lo;
}

// ---------------- GEMM via MFMA + alpha dots + fp16 H out ----------------
// MODE 1: fp32 input, full hi/lo split (3 MFMA), + fused atomic-free CSR fill (layer 1)
// MODE 0: fp16 input (exact), 2 MFMA, half LDS (layers 2-4)
template <int MODE>
__global__ __launch_bounds__(256) void k_gemm_mfma(const void* __restrict__ Xv,
                                                   const _Float16* __restrict__ Whf,
                                                   const _Float16* __restrict__ Wlf,
                                                   _Float16* __restrict__ Hh,
                                                   const float* __restrict__ asrc,
                                                   const float* __restrict__ adst,
                                                   float* __restrict__ alpha_s,
                                                   float* __restrict__ alpha_d,
                                                   const int* __restrict__ ei,
                                                   const int* __restrict__ rowptr,
                                                   const unsigned short* __restrict__ rank,
                                                   unsigned short* __restrict__ col) {
  __shared__ __align__(16) _Float16 AhL[8192];   // [w][kgf][r16][8]
  __shared__ __align__(16) _Float16 AlL[MODE ? 8192 : 1];
  const int tid = threadIdx.x;
  const int l = tid & 63;
  const int w = tid >> 6;
  const int rowbase = blockIdx.x * 64;

  #pragma unroll
  for (int p = 0; p < 4; ++p) {
    int row = p * 16 + (tid >> 4);
    int k0 = (tid & 15) * 8;
    int grow = rowbase + row;
    int idx = (((row >> 4) * 16 + (k0 >> 3)) * 16 + (row & 15)) * 8;
    if (MODE) {
      const float* X = (const float*)Xv;
      float xv[8];
      if (grow < N_NODES) {
        float4 f0 = *reinterpret_cast<const float4*>(&X[(size_t)grow * D + k0]);
        float4 f1 = *reinterpret_cast<const float4*>(&X[(size_t)grow * D + k0 + 4]);
        xv[0] = f0.x; xv[1] = f0.y; xv[2] = f0.z; xv[3] = f0.w;
        xv[4] = f1.x; xv[5] = f1.y; xv[6] = f1.z; xv[7] = f1.w;
      } else {
        #pragma unroll
        for (int j = 0; j < 8; ++j) xv[j] = 0.f;
      }
      f16x8 ah, al;
      #pragma unroll
      for (int j = 0; j < 8; ++j) {
        ah[j] = (_Float16)xv[j];
        al[j] = (_Float16)(xv[j] - (float)ah[j]);
      }
      *reinterpret_cast<f16x8*>(&AhL[idx]) = ah;
      *reinterpret_cast<f16x8*>(&AlL[idx]) = al;
    } else {
      const _Float16* X = (const _Float16*)Xv;
      f16x8 ah = {0, 0, 0, 0, 0, 0, 0, 0};
      if (grow < N_NODES)
        ah = *reinterpret_cast<const f16x8*>(&X[(size_t)grow * D + k0]);
      *reinterpret_cast<f16x8*>(&AhL[idx]) = ah;
    }
  }
  __syncthreads();

  f32x4 acc[8];
  #pragma unroll
  for (int cc = 0; cc < 8; ++cc) acc[cc] = (f32x4){0.f, 0.f, 0.f, 0.f};

  #pragma unroll
  for (int kt = 0; kt < 4; ++kt) {
    int aidx = w * 2048 + kt * 512 + l * 8;
    f16x8 ah = *reinterpret_cast<const f16x8*>(&AhL[aidx]);
    f16x8 al;
    if (MODE) al = *reinterpret_cast<const f16x8*>(&AlL[aidx]);
    #pragma unroll
    for (int cc = 0; cc < 8; ++cc) {
      int bidx = cc * 2048 + kt * 512 + l * 8;
      f16x8 bh = *reinterpret_cast<const f16x8*>(&Whf[bidx]);
      f16x8 bl = *reinterpret_cast<const f16x8*>(&Wlf[bidx]);
      acc[cc] = __builtin_amdgcn_mfma_f32_16x16x32_f16(ah, bh, acc[cc], 0, 0, 0);
      acc[cc] = __builtin_amdgcn_mfma_f32_16x16x32_f16(ah, bl, acc[cc], 0, 0, 0);
      if (MODE)
        acc[cc] = __builtin_amdgcn_mfma_f32_16x16x32_f16(al, bh, acc[cc], 0, 0, 0);
    }
  }

  const int myn = l & 15;
  const int rg4 = l >> 4;
  float asv[8], adv[8];
  #pragma unroll
  for (int cc = 0; cc < 8; ++cc) {
    asv[cc] = asrc[cc * 16 + myn];
    adv[cc] = adst[cc * 16 + myn];
  }
  #pragma unroll
  for (int reg = 0; reg < 4; ++reg) {
    int grow = rowbase + w * 16 + rg4 * 4 + reg;
    float ps = 0.f, pd = 0.f;
    #pragma unroll
    for (int cc = 0; cc < 8; ++cc) {
      float v = acc[cc][reg];
      ps = fmaf(v, asv[cc], ps);
      pd = fmaf(v, adv[cc], pd);
      if (grow < N_NODES) Hh[(size_t)grow * D + cc * 16 + myn] = (_Float16)v;
    }
    #pragma unroll
    for (int off = 1; off < 16; off <<= 1) {
      ps += __shfl_xor(ps, off);
      pd += __shfl_xor(pd, off);
    }
    if (grow < N_NODES && myn == 0) {
      alpha_s[grow] = ps;
      alpha_d[grow] = pd;
    }
  }

  // fused atomic-free CSR fill (layer 1): rank precomputed by k_count
  if (MODE) {
    int stride = gridDim.x * blockDim.x;
    for (int e = blockIdx.x * blockDim.x + tid; e < E_TOT; e += stride) {
      int src, dst;
      if (e < N_EDGES) { src = ei[e]; dst = ei[N_EDGES + e]; }
      else { src = e - N_EDGES; dst = src; }
      col[rowptr[dst] + rank[e]] = (unsigned short)src;
    }
  }
}

// ---------------- fused segment softmax + aggregate (fp16 f16x4 gather) + bias + relu ----------------
// pass 3: lane = (e2, f): f in [0,32) owns features f*4..f*4+3 (f16x4), e2 = edge parity.
// cls holds pre-scaled byte offsets (s<<8); arrays padded to mult-of-8 with (0, w=0) -> no masks.
template <int FINAL>
__global__ __launch_bounds__(256) void k_agg(const _Float16* __restrict__ Hh,
                                             const int* __restrict__ rowptr,
                                             const unsigned short* __restrict__ col,
                                             const float* __restrict__ alpha_s,
                                             const float* __restrict__ alpha_d,
                                             const float* __restrict__ bias,
                                             _Float16* __restrict__ Out,
                                             const float* __restrict__ fcW,
                                             float* __restrict__ ynode) {
  __shared__ float wls[4][MAXDEG];
  __shared__ unsigned cls[4][MAXDEG];   // byte offsets: s*256
  int wid = threadIdx.x >> 6;
  int lane = threadIdx.x & 63;
  int node = blockIdx.x * 4 + wid;
  if (node >= N_NODES) return;
  int start = rowptr[node], end = rowptr[node + 1];
  int deg = end - start;
  float ad = alpha_d[node];

  // pass 1: e into registers + scaled offsets into LDS, wave max
  float earr[4];
  float m = -1e30f;
  #pragma unroll
  for (int k = 0; k < 4; ++k) {
    int j0 = lane + k * 64;
    earr[k] = -1e30f;
    if (j0 < deg) {
      int s = col[start + j0];
      float e = alpha_s[s] + ad;
      e = e >= 0.f ? e : NEG_SLOPE * e;
      cls[wid][j0] = (unsigned)s << 8;
      earr[k] = e;
    }
  }
  m = fmaxf(fmaxf(earr[0], earr[1]), fmaxf(earr[2], earr[3]));
  for (int j0 = MAXDEG + lane; j0 < deg; j0 += 64) {
    int s = col[start + j0];
    float e = alpha_s[s] + ad;
    e = e >= 0.f ? e : NEG_SLOPE * e;
    m = fmaxf(m, e);
  }
  m = wave_max(m);

  // pass 2: weights into LDS, wave sum
  float dsum = 0.f;
  #pragma unroll
  for (int k = 0; k < 4; ++k) {
    int j0 = lane + k * 64;
    if (j0 < deg) {
      float w = expf(earr[k] - m);
      wls[wid][j0] = w;
      dsum += w;
    }
  }
  for (int j0 = MAXDEG + lane; j0 < deg; j0 += 64) {
    int s = col[start + j0];
    float e = alpha_s[s] + ad;
    e = e >= 0.f ? e : NEG_SLOPE * e;
    dsum += expf(e - m);
  }
  dsum = wave_sum(dsum);
  float inv = 1.f / (dsum + 1e-16f);

  // pad to multiple of 8 so pass 3 needs no masking (w=0, offset 0 -> node-0 row, harmless)
  int degc = deg < MAXDEG ? deg : MAXDEG;
  int degc8 = (degc + 7) & ~7;
  for (int j0 = degc + lane; j0 < degc8; j0 += 64) {
    cls[wid][j0] = 0;
    wls[wid][j0] = 0.f;
  }

  // pass 3: unmasked f16x4 gather, 2 edge-parities, 8 edges per iteration
  const unsigned fo8 = (unsigned)(lane & 31) * 8;   // byte offset of this lane's f16x4
  const int e2 = lane >> 5;
  const char* hbase = (const char*)Hh;
  f32x4 acc4 = {0.f, 0.f, 0.f, 0.f};
  for (int jj = 0; jj < degc8; jj += 8) {
    unsigned offs[4];
    float w4[4];
    f16x4 hv[4];
    #pragma unroll
    for (int u = 0; u < 4; ++u) {
      int idx = jj + u * 2 + e2;
      offs[u] = cls[wid][idx] + fo8;
      w4[u] = wls[wid][idx];
      hv[u] = *reinterpret_cast<const f16x4*>(hbase + offs[u]);
    }
    #pragma unroll
    for (int u = 0; u < 4; ++u) {
      acc4.x = fmaf((float)hv[u][0], w4[u], acc4.x);
      acc4.y = fmaf((float)hv[u][1], w4[u], acc4.y);
      acc4.z = fmaf((float)hv[u][2], w4[u], acc4.z);
      acc4.w = fmaf((float)hv[u][3], w4[u], acc4.w);
    }
  }
  for (int jj = MAXDEG; jj < deg; jj += 2) {   // cold fallback (deg > 256)
    int idx = jj + e2;
    bool ok = idx < deg;
    int s = ok ? (int)col[start + idx] : 0;
    float e = alpha_s[s] + ad;
    e = e >= 0.f ? e : NEG_SLOPE * e;
    float w = ok ? expf(e - m) : 0.f;
    f16x4 hv = *reinterpret_cast<const f16x4*>(hbase + ((unsigned)s << 8) + fo8);
    acc4.x = fmaf((float)hv[0], w, acc4.x);
    acc4.y = fmaf((float)hv[1], w, acc4.y);
    acc4.z = fmaf((float)hv[2], w, acc4.z);
    acc4.w = fmaf((float)hv[3], w, acc4.w);
  }
  // combine edge parities (lane l <-> l^32 hold the same features)
  acc4.x += __shfl_xor(acc4.x, 32);
  acc4.y += __shfl_xor(acc4.y, 32);
  acc4.z += __shfl_xor(acc4.z, 32);
  acc4.w += __shfl_xor(acc4.w, 32);

  if (FINAL) {
    float y = 0.f;
    if (e2 == 0) {
      f32x4 bv = *reinterpret_cast<const f32x4*>(&bias[(lane & 31) * 4]);
      f32x4 wv = *reinterpret_cast<const f32x4*>(&fcW[(lane & 31) * 4]);
      float o0 = fmaxf(fmaf(acc4.x, inv, bv.x), 0.f);
      float o1 = fmaxf(fmaf(acc4.y, inv, bv.y), 0.f);
      float o2 = fmaxf(fmaf(acc4.z, inv, bv.z), 0.f);
      float o3 = fmaxf(fmaf(acc4.w, inv, bv.w), 0.f);
      y = o0 * wv.x + o1 * wv.y + o2 * wv.z + o3 * wv.w;
    }
    y = wave_sum(y);
    if (lane == 0) ynode[node] = y;
  } else {
    if (e2 == 0) {
      f32x4 bv = *reinterpret_cast<const f32x4*>(&bias[(lane & 31) * 4]);
      f16x4 oh;
      oh[0] = (_Float16)fmaxf(fmaf(acc4.x, inv, bv.x), 0.f);
      oh[1] = (_Float16)fmaxf(fmaf(acc4.y, inv, bv.y), 0.f);
      oh[2] = (_Float16)fmaxf(fmaf(acc4.z, inv, bv.z), 0.f);
      oh[3] = (_Float16)fmaxf(fmaf(acc4.w, inv, bv.w), 0.f);
      *reinterpret_cast<f16x4*>((char*)Out + (size_t)node * 256 + fo8) = oh;
    }
  }
}

// ---------------- finalize: per-graph mean of ynode + bias ----------------
__global__ __launch_bounds__(256) void k_final(const float* __restrict__ ynode,
                                               const int* __restrict__ batch,
                                               const float* __restrict__ fcb,
                                               float* __restrict__ out) {
  __shared__ float sm[256];
  int b = blockIdx.x;
  int tid = threadIdx.x;
  int lo = 0, hi = N_NODES;
  while (lo < hi) { int mid = (lo + hi) >> 1; if (batch[mid] < b) lo = mid + 1; else hi = mid; }
  int s0 = lo;
  lo = 0; hi = N_NODES;
  while (lo < hi) { int mid = (lo + hi) >> 1; if (batch[mid] < b + 1) lo = mid + 1; else hi = mid; }
  int s1 = lo;
  float sum = 0.f;
  for (int n = s0 + tid; n < s1; n += 256) sum += ynode[n];
  sm[tid] = sum;
  __syncthreads();
  #pragma unroll
  for (int off = 128; off > 0; off >>= 1) {
    if (tid < off) sm[tid] += sm[tid + off];
    __syncthreads();
  }
  if (tid == 0) out[b] = sm[0] / fmaxf((float)(s1 - s0), 1.f) + fcb[0];
}

extern "C" void kernel_launch(void* const* d_in, const int* in_sizes, int n_in,
                              void* d_out, int out_size, void* d_ws, size_t ws_size,
                              hipStream_t stream) {
  const float* x = (const float*)d_in[0];
  const int* ei = (const int*)d_in[1];
  const int* batch = (const int*)d_in[2];
  const float* W[4]   = {(const float*)d_in[3], (const float*)d_in[7],
                         (const float*)d_in[11], (const float*)d_in[15]};
  const float* asr[4] = {(const float*)d_in[4], (const float*)d_in[8],
                         (const float*)d_in[12], (const float*)d_in[16]};
  const float* adt[4] = {(const float*)d_in[5], (const float*)d_in[9],
                         (const float*)d_in[13], (const float*)d_in[17]};
  const float* bs[4]  = {(const float*)d_in[6], (const float*)d_in[10],
                         (const float*)d_in[14], (const float*)d_in[18]};
  const float* fcW = (const float*)d_in[19];
  const float* fcb = (const float*)d_in[20];
  float* out = (float*)d_out;

  char* ws = (char*)d_ws;
  size_t off = 0;
  _Float16* Hh  = (_Float16*)(ws + off); off += (size_t)N_NODES * D * 2;
  _Float16* hBh = (_Float16*)(ws + off); off += (size_t)N_NODES * D * 2;
  float* alpha_s = (float*)(ws + off); off += (size_t)N_NODES * 4;
  float* alpha_d = (float*)(ws + off); off += (size_t)N_NODES * 4;
  int* cnt  = (int*)(ws + off); off += (size_t)N_NODES * 4;
  int* rowptr = (int*)(ws + off); off += (size_t)(N_NODES + 1) * 4 + 12;
  unsigned short* col = (unsigned short*)(ws + off); off += ((size_t)E_TOT * 2 + 15) & ~15ull;
  unsigned short* rank = (unsigned short*)(ws + off); off += ((size_t)E_TOT * 2 + 15) & ~15ull;
  float* ynode = (float*)(ws + off); off += (size_t)N_NODES * 4;
  int* partial = (int*)(ws + off); off += ((size_t)SCAN_GRID * 4 + 15) & ~15ull;
  _Float16* Whf[4];
  _Float16* Wlf[4];
  for (int lyr = 0; lyr < 4; ++lyr) {
    Whf[lyr] = (_Float16*)(ws + off); off += (size_t)D * D * 2;
    Wlf[lyr] = (_Float16*)(ws + off); off += (size_t)D * D * 2;
  }
  (void)ws_size; (void)in_sizes; (void)n_in; (void)out_size;

  hipMemsetAsync(cnt, 0, (size_t)N_NODES * 4, stream);
  WPtrs wp;
  for (int lyr = 0; lyr < 4; ++lyr) { wp.w[lyr] = W[lyr]; wp.h[lyr] = Whf[lyr]; wp.l[lyr] = Wlf[lyr]; }
  k_wconv_all<<<256, 256, 0, stream>>>(wp);
  int eb = (E_TOT + 255) / 256;
  k_count<<<eb, 256, 0, stream>>>(ei, cnt, rank);
  k_scan1<<<SCAN_GRID, SCAN_BLK, 0, stream>>>(cnt, rowptr, partial);
  k_scan2<<<1, 64, 0, stream>>>(partial);
  k_scan3<<<SCAN_GRID, SCAN_BLK, 0, stream>>>(rowptr, partial);

  int gb = (N_NODES + 63) / 64;
  // layer 1: gemm (fp32 input, full split) + fused atomic-free CSR fill
  k_gemm_mfma<1><<<gb, 256, 0, stream>>>(x, Whf[0], Wlf[0], Hh, asr[0], adt[0],
                                         alpha_s, alpha_d, ei, rowptr, rank, col);
  k_agg<0><<<(N_NODES + 3) / 4, 256, 0, stream>>>(Hh, rowptr, col, alpha_s, alpha_d,
                                                  bs[0], hBh, nullptr, nullptr);
  for (int l = 1; l < 4; ++l) {
    k_gemm_mfma<0><<<gb, 256, 0, stream>>>(hBh, Whf[l], Wlf[l], Hh, asr[l], adt[l],
                                           alpha_s, alpha_d, nullptr, nullptr,
                                           nullptr, nullptr);
    if (l < 3) {
      k_agg<0><<<(N_NODES + 3) / 4, 256, 0, stream>>>(Hh, rowptr, col, alpha_s, alpha_d,
                                                      bs[l], hBh, nullptr, nullptr);
    } else {
      k_agg<1><<<(N_NODES + 3) / 4, 256, 0, stream>>>(Hh, rowptr, col, alpha_s, alpha_d,
                                                      bs[l], nullptr, fcW, ynode);
    }
  }
  k_final<<<N_GRAPHS, 256, 0, stream>>>(ynode, batch, fcb, out);
}

// Round 18
// 274.910 us; speedup vs baseline: 1.5526x; 1.0590x over previous
//
#include <hip/hip_runtime.h>

#define N_NODES 50000
#define N_EDGES 800000
#define E_TOT (N_EDGES + N_NODES)
#define D 128
#define N_GRAPHS 64
#define NEG_SLOPE 0.2f
#define MAXDEG 128
#define SCAN_BLK 1024
#define SCAN_GRID ((N_NODES + SCAN_BLK - 1) / SCAN_BLK)   // 49

typedef _Float16 f16x8 __attribute__((ext_vector_type(8)));
typedef _Float16 f16x4 __attribute__((ext_vector_type(4)));
typedef float f32x4 __attribute__((ext_vector_type(4)));

__device__ __forceinline__ float wave_sum(float v) {
  #pragma unroll
  for (int off = 32; off > 0; off >>= 1) v += __shfl_xor(v, off);
  return v;
}

// ---------------- CSR build: count + per-edge rank ----------------
__global__ void k_count(const int* __restrict__ ei, int* __restrict__ cnt,
                        unsigned short* __restrict__ rank) {
  int e = blockIdx.x * blockDim.x + threadIdx.x;
  if (e >= E_TOT) return;
  int dst = (e < N_EDGES) ? ei[N_EDGES + e] : (e - N_EDGES);
  rank[e] = (unsigned short)atomicAdd(&cnt[dst], 1);
}

__global__ __launch_bounds__(SCAN_BLK) void k_scan1(const int* __restrict__ cnt,
                                                    int* __restrict__ rowptr,
                                                    int* __restrict__ partial) {
  __shared__ int sm[SCAN_BLK];
  int i = blockIdx.x * SCAN_BLK + threadIdx.x;
  int v = (i < N_NODES) ? cnt[i] : 0;
  sm[threadIdx.x] = v;
  __syncthreads();
  #pragma unroll
  for (int off = 1; off < SCAN_BLK; off <<= 1) {
    int t = (threadIdx.x >= off) ? sm[threadIdx.x - off] : 0;
    __syncthreads();
    sm[threadIdx.x] += t;
    __syncthreads();
  }
  if (i < N_NODES) rowptr[i + 1] = sm[threadIdx.x];
  if (threadIdx.x == SCAN_BLK - 1) partial[blockIdx.x] = sm[threadIdx.x];
}

__global__ void k_scan2(int* __restrict__ partial) {
  int lane = threadIdx.x;
  int v = (lane < SCAN_GRID) ? partial[lane] : 0;
  #pragma unroll
  for (int off = 1; off < 64; off <<= 1) {
    int t = __shfl_up(v, off);
    if (lane >= off) v += t;
  }
  if (lane < SCAN_GRID) partial[lane] = v;
}

__global__ __launch_bounds__(SCAN_BLK) void k_scan3(int* __restrict__ rowptr,
                                                    const int* __restrict__ partial) {
  int i = blockIdx.x * SCAN_BLK + threadIdx.x;
  if (i == 0) rowptr[0] = 0;
  if (i < N_NODES && blockIdx.x > 0) rowptr[i + 1] += partial[blockIdx.x - 1];
}

// ---------------- all-layers W -> fp16 hi/lo fragment-order conversion ----------------
struct WPtrs {
  const float* w[4];
  _Float16* h[4];
  _Float16* l[4];
};
__global__ __launch_bounds__(256) void k_wconv_all(WPtrs p) {
  int layer = blockIdx.x >> 6;
  int e = (blockIdx.x & 63) * 256 + threadIdx.x;   // 0..16383
  int k = e >> 7, n = e & 127;
  float v = p.w[layer][e];
  _Float16 h = (_Float16)v;
  _Float16 lo = (_Float16)(v - (float)h);
  int idx = (n >> 4) * 2048 + (k >> 3) * 128 + (n & 15) * 8 + (k & 7);
  p.h[layer][idx] = h;
  p.l[layer][idx] = lo;
}

// ---------------- GEMM via MFMA + alpha dots + fp16 H out ----------------
// MODE 1: fp32 input, full hi/lo split (3 MFMA), + fused atomic-free CSR fill (layer 1)
// MODE 0: fp16 input (exact), 2 MFMA, half LDS (layers 2-4)
template <int MODE>
__global__ __launch_bounds__(256) void k_gemm_mfma(const void* __restrict__ Xv,
                                                   const _Float16* __restrict__ Whf,
                                                   const _Float16* __restrict__ Wlf,
                                                   _Float16* __restrict__ Hh,
                                                   const float* __restrict__ asrc,
                                                   const float* __restrict__ adst,
                                                   float* __restrict__ alpha_s,
                                                   float* __restrict__ alpha_d,
                                                   const int* __restrict__ ei,
                                                   const int* __restrict__ rowptr,
                                                   const unsigned short* __restrict__ rank,
                                                   unsigned short* __restrict__ col) {
  __shared__ __align__(16) _Float16 AhL[8192];   // [w][kgf][r16][8]
  __shared__ __align__(16) _Float16 AlL[MODE ? 8192 : 1];
  const int tid = threadIdx.x;
  const int l = tid & 63;
  const int w = tid >> 6;
  const int rowbase = blockIdx.x * 64;

  #pragma unroll
  for (int p = 0; p < 4; ++p) {
    int row = p * 16 + (tid >> 4);
    int k0 = (tid & 15) * 8;
    int grow = rowbase + row;
    int idx = (((row >> 4) * 16 + (k0 >> 3)) * 16 + (row & 15)) * 8;
    if (MODE) {
      const float* X = (const float*)Xv;
      float xv[8];
      if (grow < N_NODES) {
        float4 f0 = *reinterpret_cast<const float4*>(&X[(size_t)grow * D + k0]);
        float4 f1 = *reinterpret_cast<const float4*>(&X[(size_t)grow * D + k0 + 4]);
        xv[0] = f0.x; xv[1] = f0.y; xv[2] = f0.z; xv[3] = f0.w;
        xv[4] = f1.x; xv[5] = f1.y; xv[6] = f1.z; xv[7] = f1.w;
      } else {
        #pragma unroll
        for (int j = 0; j < 8; ++j) xv[j] = 0.f;
      }
      f16x8 ah, al;
      #pragma unroll
      for (int j = 0; j < 8; ++j) {
        ah[j] = (_Float16)xv[j];
        al[j] = (_Float16)(xv[j] - (float)ah[j]);
      }
      *reinterpret_cast<f16x8*>(&AhL[idx]) = ah;
      *reinterpret_cast<f16x8*>(&AlL[idx]) = al;
    } else {
      const _Float16* X = (const _Float16*)Xv;
      f16x8 ah = {0, 0, 0, 0, 0, 0, 0, 0};
      if (grow < N_NODES)
        ah = *reinterpret_cast<const f16x8*>(&X[(size_t)grow * D + k0]);
      *reinterpret_cast<f16x8*>(&AhL[idx]) = ah;
    }
  }
  __syncthreads();

  f32x4 acc[8];
  #pragma unroll
  for (int cc = 0; cc < 8; ++cc) acc[cc] = (f32x4){0.f, 0.f, 0.f, 0.f};

  #pragma unroll
  for (int kt = 0; kt < 4; ++kt) {
    int aidx = w * 2048 + kt * 512 + l * 8;
    f16x8 ah = *reinterpret_cast<const f16x8*>(&AhL[aidx]);
    f16x8 al;
    if (MODE) al = *reinterpret_cast<const f16x8*>(&AlL[aidx]);
    #pragma unroll
    for (int cc = 0; cc < 8; ++cc) {
      int bidx = cc * 2048 + kt * 512 + l * 8;
      f16x8 bh = *reinterpret_cast<const f16x8*>(&Whf[bidx]);
      f16x8 bl = *reinterpret_cast<const f16x8*>(&Wlf[bidx]);
      acc[cc] = __builtin_amdgcn_mfma_f32_16x16x32_f16(ah, bh, acc[cc], 0, 0, 0);
      acc[cc] = __builtin_amdgcn_mfma_f32_16x16x32_f16(ah, bl, acc[cc], 0, 0, 0);
      if (MODE)
        acc[cc] = __builtin_amdgcn_mfma_f32_16x16x32_f16(al, bh, acc[cc], 0, 0, 0);
    }
  }

  const int myn = l & 15;
  const int rg4 = l >> 4;
  float asv[8], adv[8];
  #pragma unroll
  for (int cc = 0; cc < 8; ++cc) {
    asv[cc] = asrc[cc * 16 + myn];
    adv[cc] = adst[cc * 16 + myn];
  }
  #pragma unroll
  for (int reg = 0; reg < 4; ++reg) {
    int grow = rowbase + w * 16 + rg4 * 4 + reg;
    float ps = 0.f, pd = 0.f;
    #pragma unroll
    for (int cc = 0; cc < 8; ++cc) {
      float v = acc[cc][reg];
      ps = fmaf(v, asv[cc], ps);
      pd = fmaf(v, adv[cc], pd);
      if (grow < N_NODES) Hh[(size_t)grow * D + cc * 16 + myn] = (_Float16)v;
    }
    #pragma unroll
    for (int off = 1; off < 16; off <<= 1) {
      ps += __shfl_xor(ps, off);
      pd += __shfl_xor(pd, off);
    }
    if (grow < N_NODES && myn == 0) {
      alpha_s[grow] = ps;
      alpha_d[grow] = pd;
    }
  }

  // fused atomic-free CSR fill (layer 1): rank precomputed by k_count
  if (MODE) {
    int stride = gridDim.x * blockDim.x;
    for (int e = blockIdx.x * blockDim.x + tid; e < E_TOT; e += stride) {
      int src, dst;
      if (e < N_EDGES) { src = ei[e]; dst = ei[N_EDGES + e]; }
      else { src = e - N_EDGES; dst = src; }
      col[rowptr[dst] + rank[e]] = (unsigned short)src;
    }
  }
}

// ---------------- fused segment softmax + aggregate (fp16 f16x4 gather) ----------------
// passes 1/2: 4 nodes per wave (16 lanes each) -> 4x lane utilization on softmax phase.
// pass 3: wave walks its 4 nodes sequentially with all 64 lanes (2 edge parities x f16x4).
template <int FINAL>
__global__ __launch_bounds__(256) void k_agg(const _Float16* __restrict__ Hh,
                                             const int* __restrict__ rowptr,
                                             const unsigned short* __restrict__ col,
                                             const float* __restrict__ alpha_s,
                                             const float* __restrict__ alpha_d,
                                             const float* __restrict__ bias,
                                             _Float16* __restrict__ Out,
                                             const float* __restrict__ fcW,
                                             float* __restrict__ ynode) {
  __shared__ float wls[16][MAXDEG];
  __shared__ unsigned cls[16][MAXDEG];   // byte offsets: s*256
  __shared__ float sinv[16], smax[16];
  __shared__ int sstart[16], sdeg[16];
  const int tid = threadIdx.x;
  const int wid = tid >> 6;
  const int lane = tid & 63;
  const int sub = lane >> 4;          // node within wave (0..3)
  const int t = lane & 15;            // lane within node group
  const int slot = wid * 4 + sub;
  const int node = blockIdx.x * 16 + slot;

  // ---- passes 1/2: 16 lanes per node ----
  if (node < N_NODES) {
    int start = rowptr[node];
    int deg = rowptr[node + 1] - start;
    float ad = alpha_d[node];
    int degc = deg < MAXDEG ? deg : MAXDEG;
    float m = -1e30f;
    for (int j = t; j < degc; j += 16) {
      int s = col[start + j];
      float e = alpha_s[s] + ad;
      e = e >= 0.f ? e : NEG_SLOPE * e;
      cls[slot][j] = (unsigned)s << 8;
      wls[slot][j] = e;
      m = fmaxf(m, e);
    }
    for (int j = MAXDEG + t; j < deg; j += 16) {   // cold: deg > MAXDEG
      int s = col[start + j];
      float e = alpha_s[s] + ad;
      e = e >= 0.f ? e : NEG_SLOPE * e;
      m = fmaxf(m, e);
    }
    #pragma unroll
    for (int off = 1; off < 16; off <<= 1) m = fmaxf(m, __shfl_xor(m, off));

    float dsum = 0.f;
    for (int j = t; j < degc; j += 16) {
      float w = expf(wls[slot][j] - m);
      wls[slot][j] = w;
      dsum += w;
    }
    for (int j = MAXDEG + t; j < deg; j += 16) {   // cold
      int s = col[start + j];
      float e = alpha_s[s] + ad;
      e = e >= 0.f ? e : NEG_SLOPE * e;
      dsum += expf(e - m);
    }
    #pragma unroll
    for (int off = 1; off < 16; off <<= 1) dsum += __shfl_xor(dsum, off);

    int degc8 = (degc + 7) & ~7;                   // pad -> pass 3 unmasked
    for (int j = degc + t; j < degc8; j += 16) {
      cls[slot][j] = 0;
      wls[slot][j] = 0.f;
    }
    if (t == 0) {
      sinv[slot] = 1.f / (dsum + 1e-16f);
      smax[slot] = m;
      sstart[slot] = start;
      sdeg[slot] = deg;
    }
  } else if (t == 0) {
    sinv[slot] = 0.f; smax[slot] = 0.f; sstart[slot] = 0; sdeg[slot] = 0;
  }
  // no __syncthreads: each wave reads only its own 4 slots (wave-coherent LDS)

  // ---- pass 3: all 64 lanes per node, 4 nodes sequential ----
  const unsigned fo8 = (unsigned)(lane & 31) * 8;
  const int e2 = lane >> 5;
  const char* hbase = (const char*)Hh;
  #pragma unroll
  for (int n = 0; n < 4; ++n) {
    const int ns = wid * 4 + n;
    const int nnode = blockIdx.x * 16 + ns;
    if (nnode >= N_NODES) continue;
    const int ndeg = sdeg[ns];
    const float ninv = sinv[ns];
    int degc = ndeg < MAXDEG ? ndeg : MAXDEG;
    int degc8 = (degc + 7) & ~7;
    f32x4 acc4 = {0.f, 0.f, 0.f, 0.f};
    for (int jj = 0; jj < degc8; jj += 8) {
      unsigned offs[4];
      float w4[4];
      f16x4 hv[4];
      #pragma unroll
      for (int u = 0; u < 4; ++u) {
        int idx = jj + u * 2 + e2;
        offs[u] = cls[ns][idx] + fo8;
        w4[u] = wls[ns][idx];
        hv[u] = *reinterpret_cast<const f16x4*>(hbase + offs[u]);
      }
      #pragma unroll
      for (int u = 0; u < 4; ++u) {
        acc4.x = fmaf((float)hv[u][0], w4[u], acc4.x);
        acc4.y = fmaf((float)hv[u][1], w4[u], acc4.y);
        acc4.z = fmaf((float)hv[u][2], w4[u], acc4.z);
        acc4.w = fmaf((float)hv[u][3], w4[u], acc4.w);
      }
    }
    if (ndeg > MAXDEG) {                            // cold fallback
      const int nstart = sstart[ns];
      const float nm = smax[ns];
      const float nad = alpha_d[nnode];
      for (int jj = MAXDEG; jj < ndeg; jj += 2) {
        int idx = jj + e2;
        bool ok = idx < ndeg;
        int s = ok ? (int)col[nstart + idx] : 0;
        float e = alpha_s[s] + nad;
        e = e >= 0.f ? e : NEG_SLOPE * e;
        float w = ok ? expf(e - nm) : 0.f;
        f16x4 hv = *reinterpret_cast<const f16x4*>(hbase + ((unsigned)s << 8) + fo8);
        acc4.x = fmaf((float)hv[0], w, acc4.x);
        acc4.y = fmaf((float)hv[1], w, acc4.y);
        acc4.z = fmaf((float)hv[2], w, acc4.z);
        acc4.w = fmaf((float)hv[3], w, acc4.w);
      }
    }
    // combine edge parities (lane l <-> l^32 share features)
    acc4.x += __shfl_xor(acc4.x, 32);
    acc4.y += __shfl_xor(acc4.y, 32);
    acc4.z += __shfl_xor(acc4.z, 32);
    acc4.w += __shfl_xor(acc4.w, 32);

    if (FINAL) {
      float y = 0.f;
      if (e2 == 0) {
        f32x4 bv = *reinterpret_cast<const f32x4*>(&bias[(lane & 31) * 4]);
        f32x4 wv = *reinterpret_cast<const f32x4*>(&fcW[(lane & 31) * 4]);
        float o0 = fmaxf(fmaf(acc4.x, ninv, bv.x), 0.f);
        float o1 = fmaxf(fmaf(acc4.y, ninv, bv.y), 0.f);
        float o2 = fmaxf(fmaf(acc4.z, ninv, bv.z), 0.f);
        float o3 = fmaxf(fmaf(acc4.w, ninv, bv.w), 0.f);
        y = o0 * wv.x + o1 * wv.y + o2 * wv.z + o3 * wv.w;
      }
      y = wave_sum(y);
      if (lane == 0) ynode[nnode] = y;
    } else {
      if (e2 == 0) {
        f32x4 bv = *reinterpret_cast<const f32x4*>(&bias[(lane & 31) * 4]);
        f16x4 oh;
        oh[0] = (_Float16)fmaxf(fmaf(acc4.x, ninv, bv.x), 0.f);
        oh[1] = (_Float16)fmaxf(fmaf(acc4.y, ninv, bv.y), 0.f);
        oh[2] = (_Float16)fmaxf(fmaf(acc4.z, ninv, bv.z), 0.f);
        oh[3] = (_Float16)fmaxf(fmaf(acc4.w, ninv, bv.w), 0.f);
        *reinterpret_cast<f16x4*>((char*)Out + (size_t)nnode * 256 + fo8) = oh;
      }
    }
  }
}

// ---------------- finalize: per-graph mean of ynode + bias ----------------
__global__ __launch_bounds__(256) void k_final(const float* __restrict__ ynode,
                                               const int* __restrict__ batch,
                                               const float* __restrict__ fcb,
                                               float* __restrict__ out) {
  __shared__ float sm[256];
  int b = blockIdx.x;
  int tid = threadIdx.x;
  int lo = 0, hi = N_NODES;
  while (lo < hi) { int mid = (lo + hi) >> 1; if (batch[mid] < b) lo = mid + 1; else hi = mid; }
  int s0 = lo;
  lo = 0; hi = N_NODES;
  while (lo < hi) { int mid = (lo + hi) >> 1; if (batch[mid] < b + 1) lo = mid + 1; else hi = mid; }
  int s1 = lo;
  float sum = 0.f;
  for (int n = s0 + tid; n < s1; n += 256) sum += ynode[n];
  sm[tid] = sum;
  __syncthreads();
  #pragma unroll
  for (int off = 128; off > 0; off >>= 1) {
    if (tid < off) sm[tid] += sm[tid + off];
    __syncthreads();
  }
  if (tid == 0) out[b] = sm[0] / fmaxf((float)(s1 - s0), 1.f) + fcb[0];
}

extern "C" void kernel_launch(void* const* d_in, const int* in_sizes, int n_in,
                              void* d_out, int out_size, void* d_ws, size_t ws_size,
                              hipStream_t stream) {
  const float* x = (const float*)d_in[0];
  const int* ei = (const int*)d_in[1];
  const int* batch = (const int*)d_in[2];
  const float* W[4]   = {(const float*)d_in[3], (const float*)d_in[7],
                         (const float*)d_in[11], (const float*)d_in[15]};
  const float* asr[4] = {(const float*)d_in[4], (const float*)d_in[8],
                         (const float*)d_in[12], (const float*)d_in[16]};
  const float* adt[4] = {(const float*)d_in[5], (const float*)d_in[9],
                         (const float*)d_in[13], (const float*)d_in[17]};
  const float* bs[4]  = {(const float*)d_in[6], (const float*)d_in[10],
                         (const float*)d_in[14], (const float*)d_in[18]};
  const float* fcW = (const float*)d_in[19];
  const float* fcb = (const float*)d_in[20];
  float* out = (float*)d_out;

  char* ws = (char*)d_ws;
  size_t off = 0;
  _Float16* Hh  = (_Float16*)(ws + off); off += (size_t)N_NODES * D * 2;
  _Float16* hBh = (_Float16*)(ws + off); off += (size_t)N_NODES * D * 2;
  float* alpha_s = (float*)(ws + off); off += (size_t)N_NODES * 4;
  float* alpha_d = (float*)(ws + off); off += (size_t)N_NODES * 4;
  int* cnt  = (int*)(ws + off); off += (size_t)N_NODES * 4;
  int* rowptr = (int*)(ws + off); off += (size_t)(N_NODES + 1) * 4 + 12;
  unsigned short* col = (unsigned short*)(ws + off); off += ((size_t)E_TOT * 2 + 15) & ~15ull;
  unsigned short* rank = (unsigned short*)(ws + off); off += ((size_t)E_TOT * 2 + 15) & ~15ull;
  float* ynode = (float*)(ws + off); off += (size_t)N_NODES * 4;
  int* partial = (int*)(ws + off); off += ((size_t)SCAN_GRID * 4 + 15) & ~15ull;
  _Float16* Whf[4];
  _Float16* Wlf[4];
  for (int lyr = 0; lyr < 4; ++lyr) {
    Whf[lyr] = (_Float16*)(ws + off); off += (size_t)D * D * 2;
    Wlf[lyr] = (_Float16*)(ws + off); off += (size_t)D * D * 2;
  }
  (void)ws_size; (void)in_sizes; (void)n_in; (void)out_size;

  hipMemsetAsync(cnt, 0, (size_t)N_NODES * 4, stream);
  WPtrs wp;
  for (int lyr = 0; lyr < 4; ++lyr) { wp.w[lyr] = W[lyr]; wp.h[lyr] = Whf[lyr]; wp.l[lyr] = Wlf[lyr]; }
  k_wconv_all<<<256, 256, 0, stream>>>(wp);
  int eb = (E_TOT + 255) / 256;
  k_count<<<eb, 256, 0, stream>>>(ei, cnt, rank);
  k_scan1<<<SCAN_GRID, SCAN_BLK, 0, stream>>>(cnt, rowptr, partial);
  k_scan2<<<1, 64, 0, stream>>>(partial);
  k_scan3<<<SCAN_GRID, SCAN_BLK, 0, stream>>>(rowptr, partial);

  int gb = (N_NODES + 63) / 64;
  int ab = (N_NODES + 15) / 16;
  // layer 1: gemm (fp32 input, full split) + fused atomic-free CSR fill
  k_gemm_mfma<1><<<gb, 256, 0, stream>>>(x, Whf[0], Wlf[0], Hh, asr[0], adt[0],
                                         alpha_s, alpha_d, ei, rowptr, rank, col);
  k_agg<0><<<ab, 256, 0, stream>>>(Hh, rowptr, col, alpha_s, alpha_d,
                                   bs[0], hBh, nullptr, nullptr);
  for (int l = 1; l < 4; ++l) {
    k_gemm_mfma<0><<<gb, 256, 0, stream>>>(hBh, Whf[l], Wlf[l], Hh, asr[l], adt[l],
                                           alpha_s, alpha_d, nullptr, nullptr,
                                           nullptr, nullptr);
    if (l < 3) {
      k_agg<0><<<ab, 256, 0, stream>>>(Hh, rowptr, col, alpha_s, alpha_d,
                                       bs[l], hBh, nullptr, nullptr);
    } else {
      k_agg<1><<<ab, 256, 0, stream>>>(Hh, rowptr, col, alpha_s, alpha_d,
                                       bs[l], nullptr, fcW, ynode);
    }
  }
  k_final<<<N_GRAPHS, 256, 0, stream>>>(ynode, batch, fcb, out);
}